// Round 8
// baseline (780.727 us; speedup 1.0000x reference)
//
#include <hip/hip_runtime.h>

static constexpr int NN  = 20000;
static constexpr int NE  = 320000;
static constexpr int NTY = 4;
static constexpr int NRL = 8;
static constexpr int NB  = NRL * NN;   // 160000 bins = (rel, perm-dst)

// prep-kernel segment sizes (blocks of 256)
static constexpr int ZB = (NB + NN * 4 + 255) / 256;  // 938
static constexpr int HB = NN * 64 / 256;              // 5000
static constexpr int WB = 4 * 768;                    // 3072
static constexpr int AB = 4 * 256;                    // 1024
static constexpr int RB = 32 * 4096 / 256;            // 512
static constexpr int CB = (NN + 255) / 256;           // 79 (type-count blocks)

typedef short bf16x8 __attribute__((ext_vector_type(8)));
typedef float f32x4  __attribute__((ext_vector_type(4)));
typedef unsigned short u16x4 __attribute__((ext_vector_type(4)));

__device__ __forceinline__ unsigned short f2bf(float f) {
  unsigned u = __float_as_uint(f);
  u += 0x7fffu + ((u >> 16) & 1u);
  return (unsigned short)(u >> 16);
}
__device__ __forceinline__ float bf2f(unsigned short b) {
  return __uint_as_float(((unsigned)b) << 16);
}
__device__ __forceinline__ f32x4 mfma16(bf16x8 a, bf16x8 b, f32x4 c) {
  return __builtin_amdgcn_mfma_f32_16x16x32_bf16(a, b, c, 0, 0, 0);
}

// ---------------- node-type counting (parallel partials) ----------------
__global__ void k_tcount(const int* __restrict__ ntype, int* __restrict__ c4p) {
  __shared__ int c[4];
  if (threadIdx.x < 4) c[threadIdx.x] = 0;
  __syncthreads();
  int i = blockIdx.x * 256 + threadIdx.x;
  if (i < NN) atomicAdd(&c[ntype[i]], 1);
  __syncthreads();
  if (threadIdx.x < 4) c4p[blockIdx.x * 4 + threadIdx.x] = c[threadIdx.x];
}
__global__ void k_meta(const int* __restrict__ c4p, int* toff, int* ncur,
                       int* mt_t, int* mt_m, int* gcnt) {
  __shared__ int c4[4];
  __shared__ int ts[5];
  if (threadIdx.x < 4) {
    int s = 0;
    for (int b = 0; b < CB; ++b) s += c4p[b * 4 + threadIdx.x];
    c4[threadIdx.x] = s;
  }
  __syncthreads();
  if (threadIdx.x == 0) {
    int s = 0, s2 = 0;
    for (int t = 0; t < NTY; ++t) {
      toff[t] = s; ncur[t] = s; s += c4[t];
      ts[t] = s2; s2 += (c4[t] + 15) >> 4;
    }
    toff[NTY] = s; ts[NTY] = s2; gcnt[0] = s2;
  }
  __syncthreads();
  int nmt = ts[4];
  for (int i = threadIdx.x; i < nmt; i += 256) {
    int t = 0;
    while (t < 3 && i >= ts[t + 1]) ++t;
    mt_t[i] = t; mt_m[i] = i - ts[t];
  }
}
__global__ void k_nscatter(const int* __restrict__ key, int* cur,
                           int* nperm, int* inv) {
  int i = blockIdx.x * 256 + threadIdx.x;
  if (i < NN) {
    int p = atomicAdd(&cur[key[i]], 1);
    nperm[p] = i;
    inv[i] = p;
  }
}

// ---------------- fused prep: zero + h-cast(perm order) + weight transposes --------
__global__ void k_prep_all(const float* __restrict__ h, const float* __restrict__ Wk,
                           const float* __restrict__ Wq, const float* __restrict__ Wv,
                           const float* __restrict__ Wa, const float* __restrict__ ratt,
                           const float* __restrict__ rmsg, const int* __restrict__ nperm,
                           int* bcnt, float* denom,
                           unsigned short* hbp, unsigned short* Wt, unsigned short* At,
                           unsigned short* Att, unsigned short* Mt) {
  int b = blockIdx.x;
  if (b < ZB) {
    int i = b * 256 + threadIdx.x;
    if (i < NB) bcnt[i] = 0;
    else if (i < NB + NN * 4) denom[i - NB] = 0.f;
  } else if (b < ZB + HB) {
    int q = (b - ZB) * 256 + threadIdx.x;     // quad index over NN*64
    int p = q >> 6, c4 = q & 63;
    int node = nperm[p];
    const float* s = h + (size_t)node * 256 + c4 * 4;
    u16x4 o;
    o[0] = f2bf(s[0]); o[1] = f2bf(s[1]); o[2] = f2bf(s[2]); o[3] = f2bf(s[3]);
    *(u16x4*)(hbp + (size_t)p * 256 + c4 * 4) = o;
  } else if (b < ZB + HB + WB) {
    int bb = b - (ZB + HB);
    int j = bb % 768, t = bb / 768, i = threadIdx.x;
    const float* src; int c;
    if (j < 256)      { src = Wk; c = j; }
    else if (j < 512) { src = Wq; c = j - 256; }
    else              { src = Wv; c = j - 512; }
    Wt[(t * 768 + j) * 256 + i] = f2bf(src[(t * 256 + i) * 256 + c]);
  } else if (b < ZB + HB + WB + AB) {
    int bb = b - (ZB + HB + WB);
    int j = bb % 256, t = bb / 256, i = threadIdx.x;
    At[(t * 256 + j) * 256 + i] = f2bf(Wa[(t * 256 + i) * 256 + j]);
  } else {
    int idx = (b - (ZB + HB + WB + AB)) * 256 + threadIdx.x;
    int rh = idx >> 12, e = (idx >> 6) & 63, d = idx & 63;
    Att[idx] = f2bf(ratt[rh * 4096 + d * 64 + e]);
    Mt[idx]  = f2bf(rmsg[rh * 4096 + d * 64 + e]);
  }
}

// ---------------- edge CSR by (rel, perm-dst) ----------------
__global__ void k_bcount(const int* __restrict__ etyp, const int* __restrict__ coli,
                         const int* __restrict__ inv, int* bcnt) {
  int e = blockIdx.x * 256 + threadIdx.x;
  if (e < NE) atomicAdd(&bcnt[etyp[e] * NN + inv[coli[e]]], 1);
}
__global__ void k_scan1(const int* cnt, int* off, int* psum) {
  __shared__ int sm[256];
  int i = blockIdx.x * 256 + threadIdx.x;
  int v = cnt[i];
  sm[threadIdx.x] = v;
  __syncthreads();
  for (int d = 1; d < 256; d <<= 1) {
    int t = (threadIdx.x >= d) ? sm[threadIdx.x - d] : 0;
    __syncthreads();
    sm[threadIdx.x] += t;
    __syncthreads();
  }
  off[i] = sm[threadIdx.x] - v;
  if (threadIdx.x == 255) psum[blockIdx.x] = sm[255];
}
__global__ void k_scan2(int* psum) {
  __shared__ int sm[1024];
  int t = threadIdx.x;
  int v = (t < 625) ? psum[t] : 0;
  sm[t] = v;
  __syncthreads();
  for (int d = 1; d < 1024; d <<= 1) {
    int x = (t >= d) ? sm[t - d] : 0;
    __syncthreads();
    sm[t] += x;
    __syncthreads();
  }
  if (t < 625) psum[t] = sm[t] - v;
}
__global__ void k_scan3(int* off, int* cur, const int* psum) {
  int i = blockIdx.x * 256 + threadIdx.x;
  int v = off[i] + psum[blockIdx.x];
  off[i] = v; cur[i] = v;
  if (i == 0) off[NB] = NE;
}
// packed edge payload: (dst_local<<16) | src_perm
__global__ void k_escatter(const int* __restrict__ etyp, const int* __restrict__ rowi,
                           const int* __restrict__ coli, const int* __restrict__ inv,
                           int* cur, int* je) {
  int e = blockIdx.x * 256 + threadIdx.x;
  if (e >= NE) return;
  int pdst = inv[coli[e]];
  int bin = etyp[e] * NN + pdst;
  int j = atomicAdd(&cur[bin], 1);
  je[j] = ((pdst & 15) << 16) | inv[rowi[e]];
}

// ---------------- K1: typed K/Q/V projection (perm space, coalesced) ----------------
__global__ __launch_bounds__(256) void k_gemm_kqv(
    const unsigned short* __restrict__ hbp, const unsigned short* __restrict__ Wt,
    const int* __restrict__ toff, const int* __restrict__ mt_t,
    const int* __restrict__ mt_m, const int* __restrict__ gcnt,
    unsigned short* __restrict__ kvb, unsigned short* __restrict__ qb) {
  int mtile = blockIdx.x;
  if (mtile >= gcnt[0]) return;
  int wave = threadIdx.x >> 6, lane = threadIdx.x & 63;
  int t = mt_t[mtile], tm = mt_m[mtile];
  int base = toff[t], cnt = toff[t + 1] - base;
  int lr = lane & 15, kq = lane >> 4;
  int arow = tm * 16 + lr;
  int prow = base + (arow < cnt ? arow : cnt - 1);
  const unsigned short* aptr = hbp + (size_t)prow * 256 + kq * 8;
  bf16x8 af[8];
#pragma unroll
  for (int s = 0; s < 8; ++s) af[s] = *(const bf16x8*)(aptr + s * 32);
  int pr[4]; bool wr[4];
#pragma unroll
  for (int i = 0; i < 4; ++i) {
    int crow = tm * 16 + kq * 4 + i;
    wr[i] = crow < cnt;
    pr[i] = base + (wr[i] ? crow : 0);
  }
  for (int j = 0; j < 12; ++j) {
    int tn = wave * 12 + j;
    const unsigned short* bptr = Wt + ((t * 768 + tn * 16 + lr) * 256) + kq * 8;
    f32x4 acc = {0.f, 0.f, 0.f, 0.f};
#pragma unroll
    for (int s = 0; s < 8; ++s)
      acc = mfma16(af[s], *(const bf16x8*)(bptr + s * 32), acc);
    int ccol = tn * 16 + lr;
#pragma unroll
    for (int i = 0; i < 4; ++i) {
      if (wr[i]) {
        unsigned short v = f2bf(acc[i]);
        if (ccol < 256)
          kvb[(size_t)pr[i] * 512 + (ccol >> 6) * 128 + (ccol & 63)] = v;
        else if (ccol < 512)
          qb[(size_t)pr[i] * 256 + (ccol - 256)] = v;
        else {
          int c = ccol - 512;
          kvb[(size_t)pr[i] * 512 + (c >> 6) * 128 + 64 + (c & 63)] = v;
        }
      }
    }
  }
}

// ---------------- K2: mega — edge-parallel wave-uniform union loop ------------------
// block = (dst-tile of 16, relation-quarter = 2 rels); wave role: head h for MFMA
// phases; edge loop partitions lanes as (edge-slot, head, dim-quarter).
__global__ __launch_bounds__(256) void k_mega(
    const int* __restrict__ boff, const int* __restrict__ je,
    const unsigned short* __restrict__ qb, const unsigned short* __restrict__ kvb,
    const unsigned short* __restrict__ Att, const unsigned short* __restrict__ Mt,
    const float* __restrict__ pri, unsigned short* __restrict__ aggh,
    float* __restrict__ denom) {
  __shared__ float qsh[4][16][68];   // f32 qt: [head][dst_local][dim] (+4 pad)
  __shared__ float acc[4][16][68];   // f32 accum: [head][dst_local][dim]
  __shared__ float dsum[4][16];
  int dt = blockIdx.x >> 2, quarter = blockIdx.x & 3;
  int h = threadIdx.x >> 6, lane = threadIdx.x & 63;
  int lr = lane & 15, kq = lane >> 4;
  int dtl = dt * 16 + lr;
  int r0 = quarter * 2;
  // edge-loop lane mapping
  int el = lane >> 4;          // edge slot 0..3
  int eh = (lane >> 2) & 3;    // head
  int ekq = lane & 3;          // dim quarter
  const unsigned short* ap = qb + (size_t)dtl * 256 + h * 64 + kq * 8;
  bf16x8 aq0 = *(const bf16x8*)ap;
  bf16x8 aq1 = *(const bf16x8*)(ap + 32);
  if (lane < 16) dsum[h][lane] = 0.f;
  f32x4 C[4] = {{0.f,0.f,0.f,0.f},{0.f,0.f,0.f,0.f},{0.f,0.f,0.f,0.f},{0.f,0.f,0.f,0.f}};
  for (int rr = 0; rr < 2; ++rr) {
    int r = r0 + rr;
    int rh = r * 4 + h;
    int jb = boff[r * NN + dt * 16];
    int jend = boff[r * NN + dt * 16 + 16];
    // phase 1: qt = q @ A_r^T via MFMA -> qsh (f32, transposed); zero acc
#pragma unroll
    for (int tn = 0; tn < 4; ++tn) {
      const unsigned short* bp = Att + ((rh * 64 + tn * 16 + lr) * 64) + kq * 8;
      f32x4 a = {0.f, 0.f, 0.f, 0.f};
      a = mfma16(aq0, *(const bf16x8*)bp, a);
      a = mfma16(aq1, *(const bf16x8*)(bp + 32), a);
#pragma unroll
      for (int i = 0; i < 4; ++i)
        qsh[h][kq * 4 + i][tn * 16 + lr] = a[i];
    }
    for (int u = lane; u < 16 * 68; u += 64) (&acc[h][0][0])[u] = 0.f;
    __syncthreads();
    // phase 2: wave-uniform edge loop; wave w handles edges jb+w*4+el, stride 16
    if (jb < jend) {
      float prs = pri[r * 4 + eh] * 0.125f;
      for (int j = jb + h * 4; j < jend; j += 16) {
        int jj = j + el;
        bool act = jj < jend;
        int pk = je[act ? jj : jend - 1];
        int src = pk & 0xffff, dl = (pk >> 16) & 15;
        const unsigned short* kp = kvb + (size_t)src * 512 + eh * 128 + ekq * 8;
        bf16x8 kl = *(const bf16x8*)kp;
        bf16x8 kh = *(const bf16x8*)(kp + 32);
        bf16x8 vl = *(const bf16x8*)(kp + 64);
        bf16x8 vh = *(const bf16x8*)(kp + 96);
        const float* qlo = &qsh[eh][dl][ekq * 8];
        const float* qhi = &qsh[eh][dl][32 + ekq * 8];
        float s = 0.f;
#pragma unroll
        for (int m = 0; m < 8; ++m)
          s += qlo[m] * bf2f((unsigned short)kl[m]) +
               qhi[m] * bf2f((unsigned short)kh[m]);
        s += __shfl_xor(s, 1);
        s += __shfl_xor(s, 2);
        float ex = act ? __expf(s * prs) : 0.f;
        if (ekq == 0) atomicAdd(&dsum[eh][dl], ex);
        float* alo = &acc[eh][dl][ekq * 8];
        float* ahi = &acc[eh][dl][32 + ekq * 8];
#pragma unroll
        for (int m = 0; m < 8; ++m) {
          atomicAdd(&alo[m], ex * bf2f((unsigned short)vl[m]));
          atomicAdd(&ahi[m], ex * bf2f((unsigned short)vh[m]));
        }
      }
    }
    __syncthreads();
    // phase 3: M-transform from acc (wave = head)
    bf16x8 m0, m1;
#pragma unroll
    for (int m = 0; m < 8; ++m) {
      m0[m] = (short)f2bf(acc[h][lr][kq * 8 + m]);
      m1[m] = (short)f2bf(acc[h][lr][32 + kq * 8 + m]);
    }
#pragma unroll
    for (int tn = 0; tn < 4; ++tn) {
      const unsigned short* bp = Mt + ((rh * 64 + tn * 16 + lr) * 64) + kq * 8;
      C[tn] = mfma16(m0, *(const bf16x8*)bp, C[tn]);
      C[tn] = mfma16(m1, *(const bf16x8*)(bp + 32), C[tn]);
    }
    __syncthreads();   // protect acc/qsh reuse by next rel
  }
  if (kq == 0) atomicAdd(&denom[dtl * 4 + h], dsum[h][lr]);
#pragma unroll
  for (int tn = 0; tn < 4; ++tn)
#pragma unroll
    for (int i = 0; i < 4; ++i)
      aggh[((size_t)quarter * NN + dt * 16 + kq * 4 + i) * 256 + h * 64 + tn * 16 + lr] =
          f2bf(C[tn][i]);
}

// ---------------- K3: final typed projection + normalize + sigmoid(skip) ------------
__global__ __launch_bounds__(256) void k_gemm_out(
    const unsigned short* __restrict__ aggh, const float* __restrict__ denom,
    const unsigned short* __restrict__ At,
    const int* __restrict__ nperm, const int* __restrict__ toff,
    const int* __restrict__ mt_t, const int* __restrict__ mt_m,
    const int* __restrict__ gcnt,
    const float* __restrict__ skip, float* __restrict__ out) {
  int mtile = blockIdx.x;
  if (mtile >= gcnt[0]) return;
  int wave = threadIdx.x >> 6, lane = threadIdx.x & 63;
  int t = mt_t[mtile], tm = mt_m[mtile];
  int base = toff[t], cnt = toff[t + 1] - base;
  int lr = lane & 15, kq = lane >> 4;
  int arow = tm * 16 + lr;
  int prow = base + (arow < cnt ? arow : cnt - 1);
  float dn[4];
#pragma unroll
  for (int hh = 0; hh < 4; ++hh) {
    float d = denom[prow * 4 + hh];
    dn[hh] = d > 0.f ? 1.f / d : 0.f;
  }
  const unsigned short* g = aggh + (size_t)prow * 256 + kq * 8;
  bf16x8 af[8];
#pragma unroll
  for (int s = 0; s < 8; ++s) {
    bf16x8 x0 = *(const bf16x8*)(g + s * 32);
    bf16x8 x1 = *(const bf16x8*)(g + (size_t)NN * 256 + s * 32);
    bf16x8 x2 = *(const bf16x8*)(g + (size_t)2 * NN * 256 + s * 32);
    bf16x8 x3 = *(const bf16x8*)(g + (size_t)3 * NN * 256 + s * 32);
    float dv = dn[(kq * 8 + s * 32) >> 6];
#pragma unroll
    for (int m = 0; m < 8; ++m)
      af[s][m] = (short)f2bf((bf2f((unsigned short)x0[m]) + bf2f((unsigned short)x1[m]) +
                              bf2f((unsigned short)x2[m]) + bf2f((unsigned short)x3[m])) * dv);
  }
  int nd[4]; bool wr[4];
#pragma unroll
  for (int i = 0; i < 4; ++i) {
    int crow = tm * 16 + kq * 4 + i;
    wr[i] = crow < cnt;
    nd[i] = nperm[base + (wr[i] ? crow : 0)];
  }
  float sg = 1.f / (1.f + __expf(-skip[t]));
  for (int j = 0; j < 4; ++j) {
    int tn = wave * 4 + j;
    const unsigned short* bptr = At + (t * 256 + tn * 16 + lr) * 256 + kq * 8;
    f32x4 acc = {0.f, 0.f, 0.f, 0.f};
#pragma unroll
    for (int s = 0; s < 8; ++s)
      acc = mfma16(af[s], *(const bf16x8*)(bptr + s * 32), acc);
    int ccol = tn * 16 + lr;
#pragma unroll
    for (int i = 0; i < 4; ++i)
      if (wr[i]) out[nd[i] * 256 + ccol] = acc[i] * sg;
  }
}

extern "C" void kernel_launch(void* const* d_in, const int* in_sizes, int n_in,
                              void* d_out, int out_size, void* d_ws, size_t ws_size,
                              hipStream_t stream) {
  (void)in_sizes; (void)n_in; (void)out_size; (void)ws_size;
  const float* h    = (const float*)d_in[0];
  const float* Wk   = (const float*)d_in[1];
  const float* Wq   = (const float*)d_in[2];
  const float* Wv   = (const float*)d_in[3];
  const float* Wa   = (const float*)d_in[4];
  const float* ratt = (const float*)d_in[5];
  const float* rmsg = (const float*)d_in[6];
  const float* pri  = (const float*)d_in[7];
  const float* skp  = (const float*)d_in[8];
  const int* ntype  = (const int*)d_in[9];
  const int* etyp   = (const int*)d_in[10];
  const int* rowi   = (const int*)d_in[11];
  const int* coli   = (const int*)d_in[12];
  float* out = (float*)d_out;

  char* p = (char*)d_ws;
  auto alloc = [&](size_t bytes) {
    void* q = (void*)p;
    p += (bytes + 255) & ~(size_t)255;
    return q;
  };
  unsigned short* hbp  = (unsigned short*)alloc((size_t)NN * 256 * 2);
  unsigned short* Wt   = (unsigned short*)alloc((size_t)4 * 768 * 256 * 2);
  unsigned short* At   = (unsigned short*)alloc((size_t)4 * 256 * 256 * 2);
  unsigned short* Att  = (unsigned short*)alloc((size_t)32 * 4096 * 2);
  unsigned short* Mt   = (unsigned short*)alloc((size_t)32 * 4096 * 2);
  unsigned short* kvb  = (unsigned short*)alloc((size_t)NN * 512 * 2);
  unsigned short* qb   = (unsigned short*)alloc((size_t)NN * 256 * 2);
  unsigned short* aggh = (unsigned short*)alloc((size_t)4 * NN * 256 * 2);
  float* denom = (float*)alloc((size_t)NN * 4 * 4);
  int* toff  = (int*)alloc(32);
  int* ncur  = (int*)alloc(16);
  int* c4p   = (int*)alloc((size_t)CB * 4 * 4);
  int* nperm = (int*)alloc((size_t)NN * 4);
  int* inv   = (int*)alloc((size_t)NN * 4);
  int* bcnt  = (int*)alloc((size_t)NB * 4);
  int* boff  = (int*)alloc((size_t)(NB + 1) * 4);
  int* bcur  = (int*)alloc((size_t)NB * 4);
  int* psum  = (int*)alloc((size_t)625 * 4);
  int* je    = (int*)alloc((size_t)NE * 4);
  int* mt_t = (int*)alloc((size_t)1253 * 4);
  int* mt_m = (int*)alloc((size_t)1253 * 4);
  int* gcnt = (int*)alloc(32);

  // node buckets (perm space)
  k_tcount<<<CB, 256, 0, stream>>>(ntype, c4p);
  k_meta<<<1, 256, 0, stream>>>(c4p, toff, ncur, mt_t, mt_m, gcnt);
  k_nscatter<<<CB, 256, 0, stream>>>(ntype, ncur, nperm, inv);

  // fused prep (zero + h-cast-perm + weight transposes)
  k_prep_all<<<ZB + HB + WB + AB + RB, 256, 0, stream>>>(
      h, Wk, Wq, Wv, Wa, ratt, rmsg, nperm, bcnt, denom, hbp, Wt, At, Att, Mt);

  // edge CSR by (rel, perm-dst)
  k_bcount<<<(NE + 255) / 256, 256, 0, stream>>>(etyp, coli, inv, bcnt);
  k_scan1<<<625, 256, 0, stream>>>(bcnt, boff, psum);
  k_scan2<<<1, 1024, 0, stream>>>(psum);
  k_scan3<<<625, 256, 0, stream>>>(boff, bcur, psum);
  k_escatter<<<(NE + 255) / 256, 256, 0, stream>>>(etyp, rowi, coli, inv, bcur, je);

  // main pipeline
  k_gemm_kqv<<<1253, 256, 0, stream>>>(hbp, Wt, toff, mt_t, mt_m, gcnt, kvb, qb);
  k_mega<<<5000, 256, 0, stream>>>(boff, je, qb, kvb, Att, Mt, pri, aggh, denom);
  k_gemm_out<<<1253, 256, 0, stream>>>(aggh, denom, At, nperm, toff, mt_t, mt_m, gcnt,
                                       skp, out);
}

// Round 9
// 410.732 us; speedup vs baseline: 1.9008x; 1.9008x over previous
//
#include <hip/hip_runtime.h>

static constexpr int NN  = 20000;
static constexpr int NE  = 320000;
static constexpr int NTY = 4;
static constexpr int NRL = 8;
static constexpr int NB  = NRL * NN;   // 160000 bins = (rel, perm-dst)

// prep-kernel segment sizes (blocks of 256)
static constexpr int ZB = (NB + NN * 4 + 255) / 256;  // 938
static constexpr int HB = NN * 64 / 256;              // 5000
static constexpr int WB = 4 * 768;                    // 3072
static constexpr int AB = 4 * 256;                    // 1024
static constexpr int RB = 32 * 4096 / 256;            // 512
static constexpr int CB = (NN + 255) / 256;           // 79 (type-count blocks)

typedef short bf16x8 __attribute__((ext_vector_type(8)));
typedef float f32x4  __attribute__((ext_vector_type(4)));
typedef unsigned short u16x4 __attribute__((ext_vector_type(4)));

__device__ __forceinline__ unsigned short f2bf(float f) {
  unsigned u = __float_as_uint(f);
  u += 0x7fffu + ((u >> 16) & 1u);
  return (unsigned short)(u >> 16);
}
__device__ __forceinline__ float bf2f(unsigned short b) {
  return __uint_as_float(((unsigned)b) << 16);
}
__device__ __forceinline__ f32x4 mfma16(bf16x8 a, bf16x8 b, f32x4 c) {
  return __builtin_amdgcn_mfma_f32_16x16x32_bf16(a, b, c, 0, 0, 0);
}

// ---------------- node-type counting (parallel partials) ----------------
__global__ void k_tcount(const int* __restrict__ ntype, int* __restrict__ c4p) {
  __shared__ int c[4];
  if (threadIdx.x < 4) c[threadIdx.x] = 0;
  __syncthreads();
  int i = blockIdx.x * 256 + threadIdx.x;
  if (i < NN) atomicAdd(&c[ntype[i]], 1);
  __syncthreads();
  if (threadIdx.x < 4) c4p[blockIdx.x * 4 + threadIdx.x] = c[threadIdx.x];
}
__global__ void k_meta(const int* __restrict__ c4p, int* toff, int* ncur,
                       int* mt_t, int* mt_m, int* gcnt) {
  __shared__ int c4[4];
  __shared__ int ts[5];
  if (threadIdx.x < 4) {
    int s = 0;
    for (int b = 0; b < CB; ++b) s += c4p[b * 4 + threadIdx.x];
    c4[threadIdx.x] = s;
  }
  __syncthreads();
  if (threadIdx.x == 0) {
    int s = 0, s2 = 0;
    for (int t = 0; t < NTY; ++t) {
      toff[t] = s; ncur[t] = s; s += c4[t];
      ts[t] = s2; s2 += (c4[t] + 15) >> 4;
    }
    toff[NTY] = s; ts[NTY] = s2; gcnt[0] = s2;
  }
  __syncthreads();
  int nmt = ts[4];
  for (int i = threadIdx.x; i < nmt; i += 256) {
    int t = 0;
    while (t < 3 && i >= ts[t + 1]) ++t;
    mt_t[i] = t; mt_m[i] = i - ts[t];
  }
}
__global__ void k_nscatter(const int* __restrict__ key, int* cur,
                           int* nperm, int* inv) {
  int i = blockIdx.x * 256 + threadIdx.x;
  if (i < NN) {
    int p = atomicAdd(&cur[key[i]], 1);
    nperm[p] = i;
    inv[i] = p;
  }
}

// ---------------- fused prep: zero + h-cast(perm order) + weight transposes --------
__global__ void k_prep_all(const float* __restrict__ h, const float* __restrict__ Wk,
                           const float* __restrict__ Wq, const float* __restrict__ Wv,
                           const float* __restrict__ Wa, const float* __restrict__ ratt,
                           const float* __restrict__ rmsg, const int* __restrict__ nperm,
                           int* bcnt, float* denom,
                           unsigned short* hbp, unsigned short* Wt, unsigned short* At,
                           unsigned short* Att, unsigned short* Mt) {
  int b = blockIdx.x;
  if (b < ZB) {
    int i = b * 256 + threadIdx.x;
    if (i < NB) bcnt[i] = 0;
    else if (i < NB + NN * 4) denom[i - NB] = 0.f;
  } else if (b < ZB + HB) {
    int q = (b - ZB) * 256 + threadIdx.x;     // quad index over NN*64
    int p = q >> 6, c4 = q & 63;
    int node = nperm[p];
    const float* s = h + (size_t)node * 256 + c4 * 4;
    u16x4 o;
    o[0] = f2bf(s[0]); o[1] = f2bf(s[1]); o[2] = f2bf(s[2]); o[3] = f2bf(s[3]);
    *(u16x4*)(hbp + (size_t)p * 256 + c4 * 4) = o;
  } else if (b < ZB + HB + WB) {
    int bb = b - (ZB + HB);
    int j = bb % 768, t = bb / 768, i = threadIdx.x;
    const float* src; int c;
    if (j < 256)      { src = Wk; c = j; }
    else if (j < 512) { src = Wq; c = j - 256; }
    else              { src = Wv; c = j - 512; }
    Wt[(t * 768 + j) * 256 + i] = f2bf(src[(t * 256 + i) * 256 + c]);
  } else if (b < ZB + HB + WB + AB) {
    int bb = b - (ZB + HB + WB);
    int j = bb % 256, t = bb / 256, i = threadIdx.x;
    At[(t * 256 + j) * 256 + i] = f2bf(Wa[(t * 256 + i) * 256 + j]);
  } else {
    int idx = (b - (ZB + HB + WB + AB)) * 256 + threadIdx.x;
    int rh = idx >> 12, e = (idx >> 6) & 63, d = idx & 63;
    Att[idx] = f2bf(ratt[rh * 4096 + d * 64 + e]);
    Mt[idx]  = f2bf(rmsg[rh * 4096 + d * 64 + e]);
  }
}

// ---------------- edge CSR by (rel, perm-dst) ----------------
__global__ void k_bcount(const int* __restrict__ etyp, const int* __restrict__ coli,
                         const int* __restrict__ inv, int* bcnt) {
  int e = blockIdx.x * 256 + threadIdx.x;
  if (e < NE) atomicAdd(&bcnt[etyp[e] * NN + inv[coli[e]]], 1);
}
__global__ void k_scan1(const int* cnt, int* off, int* psum) {
  __shared__ int sm[256];
  int i = blockIdx.x * 256 + threadIdx.x;
  int v = cnt[i];
  sm[threadIdx.x] = v;
  __syncthreads();
  for (int d = 1; d < 256; d <<= 1) {
    int t = (threadIdx.x >= d) ? sm[threadIdx.x - d] : 0;
    __syncthreads();
    sm[threadIdx.x] += t;
    __syncthreads();
  }
  off[i] = sm[threadIdx.x] - v;
  if (threadIdx.x == 255) psum[blockIdx.x] = sm[255];
}
__global__ void k_scan2(int* psum) {
  __shared__ int sm[1024];
  int t = threadIdx.x;
  int v = (t < 625) ? psum[t] : 0;
  sm[t] = v;
  __syncthreads();
  for (int d = 1; d < 1024; d <<= 1) {
    int x = (t >= d) ? sm[t - d] : 0;
    __syncthreads();
    sm[t] += x;
    __syncthreads();
  }
  if (t < 625) psum[t] = sm[t] - v;
}
__global__ void k_scan3(int* off, int* cur, const int* psum) {
  int i = blockIdx.x * 256 + threadIdx.x;
  int v = off[i] + psum[blockIdx.x];
  off[i] = v; cur[i] = v;
  if (i == 0) off[NB] = NE;
}
__global__ void k_escatter(const int* __restrict__ etyp, const int* __restrict__ rowi,
                           const int* __restrict__ coli, const int* __restrict__ inv,
                           int* cur, int* je) {
  int e = blockIdx.x * 256 + threadIdx.x;
  if (e >= NE) return;
  int bin = etyp[e] * NN + inv[coli[e]];
  int j = atomicAdd(&cur[bin], 1);
  je[j] = inv[rowi[e]];
}

// ---------------- K1: typed K/Q/V projection (perm space, coalesced) ----------------
__global__ __launch_bounds__(256) void k_gemm_kqv(
    const unsigned short* __restrict__ hbp, const unsigned short* __restrict__ Wt,
    const int* __restrict__ toff, const int* __restrict__ mt_t,
    const int* __restrict__ mt_m, const int* __restrict__ gcnt,
    unsigned short* __restrict__ kvb, unsigned short* __restrict__ qb) {
  int mtile = blockIdx.x;
  if (mtile >= gcnt[0]) return;
  int wave = threadIdx.x >> 6, lane = threadIdx.x & 63;
  int t = mt_t[mtile], tm = mt_m[mtile];
  int base = toff[t], cnt = toff[t + 1] - base;
  int lr = lane & 15, kq = lane >> 4;
  int arow = tm * 16 + lr;
  int prow = base + (arow < cnt ? arow : cnt - 1);
  const unsigned short* aptr = hbp + (size_t)prow * 256 + kq * 8;
  bf16x8 af[8];
#pragma unroll
  for (int s = 0; s < 8; ++s) af[s] = *(const bf16x8*)(aptr + s * 32);
  int pr[4]; bool wr[4];
#pragma unroll
  for (int i = 0; i < 4; ++i) {
    int crow = tm * 16 + kq * 4 + i;
    wr[i] = crow < cnt;
    pr[i] = base + (wr[i] ? crow : 0);
  }
  for (int j = 0; j < 12; ++j) {
    int tn = wave * 12 + j;
    const unsigned short* bptr = Wt + ((t * 768 + tn * 16 + lr) * 256) + kq * 8;
    f32x4 acc = {0.f, 0.f, 0.f, 0.f};
#pragma unroll
    for (int s = 0; s < 8; ++s)
      acc = mfma16(af[s], *(const bf16x8*)(bptr + s * 32), acc);
    int ccol = tn * 16 + lr;
#pragma unroll
    for (int i = 0; i < 4; ++i) {
      if (wr[i]) {
        unsigned short v = f2bf(acc[i]);
        if (ccol < 256)
          kvb[(size_t)pr[i] * 512 + (ccol >> 6) * 128 + (ccol & 63)] = v;
        else if (ccol < 512)
          qb[(size_t)pr[i] * 256 + (ccol - 256)] = v;
        else {
          int c = ccol - 512;
          kvb[(size_t)pr[i] * 512 + (c >> 6) * 128 + 64 + (c & 63)] = v;
        }
      }
    }
  }
}

// ---------------- K2: mega — 32 bins/wave, 2-lane dim split, reg accumulators -------
// block = (dst-tile of 32, relation-quarter = 2 rels); wave = head.
// Edge loop: lane = (lr32 = bin, kq1 = dim half). All LDS slabs wave-private.
__global__ __launch_bounds__(256) void k_mega(
    const int* __restrict__ boff, const int* __restrict__ je,
    const unsigned short* __restrict__ qb, const unsigned short* __restrict__ kvb,
    const unsigned short* __restrict__ Att, const unsigned short* __restrict__ Mt,
    const float* __restrict__ pri, unsigned short* __restrict__ aggh,
    float* __restrict__ denom) {
  __shared__ float qsh[4][32][68];   // [head][dst_local][dim] f32, stride 68 (16B-mult)
  int dt = blockIdx.x >> 2, quarter = blockIdx.x & 3;
  int h = threadIdx.x >> 6, lane = threadIdx.x & 63;
  int lr16 = lane & 15, kq4 = lane >> 4;    // MFMA mapping
  int lr32 = lane & 31, kq1 = lane >> 5;    // edge-loop mapping
  int r0 = quarter * 2;
  float dtot = 0.f;
  f32x4 C[2][4] = {{{0.f,0.f,0.f,0.f},{0.f,0.f,0.f,0.f},{0.f,0.f,0.f,0.f},{0.f,0.f,0.f,0.f}},
                   {{0.f,0.f,0.f,0.f},{0.f,0.f,0.f,0.f},{0.f,0.f,0.f,0.f},{0.f,0.f,0.f,0.f}}};
  for (int rr = 0; rr < 2; ++rr) {
    int r = r0 + rr;
    int rh = r * 4 + h;
    int bin = r * NN + dt * 32 + lr32;
    int b0 = boff[bin], b1 = boff[bin + 1];   // coalesced, hoisted over phase 1
    // ---- phase 1: qt = q @ A_r^T via MFMA (two 16-row halves) -> qsh f32 ----
#pragma unroll
    for (int hf = 0; hf < 2; ++hf) {
      const unsigned short* ap = qb + (size_t)(dt * 32 + hf * 16 + lr16) * 256 + h * 64 + kq4 * 8;
      bf16x8 aq0 = *(const bf16x8*)ap;
      bf16x8 aq1 = *(const bf16x8*)(ap + 32);
#pragma unroll
      for (int tn = 0; tn < 4; ++tn) {
        const unsigned short* bp = Att + ((rh * 64 + tn * 16 + lr16) * 64) + kq4 * 8;
        f32x4 a = {0.f, 0.f, 0.f, 0.f};
        a = mfma16(aq0, *(const bf16x8*)bp, a);
        a = mfma16(aq1, *(const bf16x8*)(bp + 32), a);
#pragma unroll
        for (int i = 0; i < 4; ++i)
          qsh[h][hf * 16 + kq4 * 4 + i][tn * 16 + lr16] = a[i];
      }
    }
    // ---- qt -> registers (wave-local LDS round trip, same wave ordering) ----
    float qt[32];
#pragma unroll
    for (int m = 0; m < 32; m += 4) {
      f32x4 v = *(const f32x4*)&qsh[h][lr32][kq1 * 32 + m];
      qt[m] = v[0]; qt[m + 1] = v[1]; qt[m + 2] = v[2]; qt[m + 3] = v[3];
    }
    // ---- phase 2: per-lane bin walk; lane owns (bin lr32, dim half kq1) ----
    float acc[32];
#pragma unroll
    for (int m = 0; m < 32; ++m) acc[m] = 0.f;
    float prs = pri[rh] * 0.125f;
    for (int j = b0; j < b1; ++j) {
      int src = je[j];
      const unsigned short* kp = kvb + (size_t)src * 512 + h * 128 + kq1 * 32;
      bf16x8 k0 = *(const bf16x8*)kp;
      bf16x8 k1 = *(const bf16x8*)(kp + 8);
      bf16x8 k2 = *(const bf16x8*)(kp + 16);
      bf16x8 k3 = *(const bf16x8*)(kp + 24);
      bf16x8 v0 = *(const bf16x8*)(kp + 64);
      bf16x8 v1 = *(const bf16x8*)(kp + 72);
      bf16x8 v2 = *(const bf16x8*)(kp + 80);
      bf16x8 v3 = *(const bf16x8*)(kp + 88);
      float s = 0.f;
#pragma unroll
      for (int m = 0; m < 8; ++m) {
        s += qt[m]      * bf2f((unsigned short)k0[m]);
        s += qt[8 + m]  * bf2f((unsigned short)k1[m]);
        s += qt[16 + m] * bf2f((unsigned short)k2[m]);
        s += qt[24 + m] * bf2f((unsigned short)k3[m]);
      }
      s += __shfl_xor(s, 32);
      float ex = __expf(s * prs);
      dtot += ex;
#pragma unroll
      for (int m = 0; m < 8; ++m) {
        acc[m]      += ex * bf2f((unsigned short)v0[m]);
        acc[8 + m]  += ex * bf2f((unsigned short)v1[m]);
        acc[16 + m] += ex * bf2f((unsigned short)v2[m]);
        acc[24 + m] += ex * bf2f((unsigned short)v3[m]);
      }
    }
    // ---- phase 3: stage acc -> qsh (clobbers qt, no longer needed), M-transform ----
#pragma unroll
    for (int m = 0; m < 32; m += 4) {
      f32x4 v = {acc[m], acc[m + 1], acc[m + 2], acc[m + 3]};
      *(f32x4*)&qsh[h][lr32][kq1 * 32 + m] = v;
    }
#pragma unroll
    for (int hf = 0; hf < 2; ++hf) {
      bf16x8 m0, m1;
#pragma unroll
      for (int m = 0; m < 8; ++m) {
        m0[m] = (short)f2bf(qsh[h][hf * 16 + lr16][kq4 * 8 + m]);
        m1[m] = (short)f2bf(qsh[h][hf * 16 + lr16][32 + kq4 * 8 + m]);
      }
#pragma unroll
      for (int tn = 0; tn < 4; ++tn) {
        const unsigned short* bp = Mt + ((rh * 64 + tn * 16 + lr16) * 64) + kq4 * 8;
        C[hf][tn] = mfma16(m0, *(const bf16x8*)bp, C[hf][tn]);
        C[hf][tn] = mfma16(m1, *(const bf16x8*)(bp + 32), C[hf][tn]);
      }
    }
  }
  // dtot: lanes kq1==0 hold full per-bin sums (score was shfl-combined; ex identical
  // on both halves, accumulate once)
  if (kq1 == 0) atomicAdd(&denom[(dt * 32 + lr32) * 4 + h], dtot);
#pragma unroll
  for (int hf = 0; hf < 2; ++hf)
#pragma unroll
    for (int tn = 0; tn < 4; ++tn)
#pragma unroll
      for (int i = 0; i < 4; ++i)
        aggh[((size_t)quarter * NN + dt * 32 + hf * 16 + kq4 * 4 + i) * 256 +
             h * 64 + tn * 16 + lr16] = f2bf(C[hf][tn][i]);
}

// ---------------- K3: final typed projection + normalize + sigmoid(skip) ------------
__global__ __launch_bounds__(256) void k_gemm_out(
    const unsigned short* __restrict__ aggh, const float* __restrict__ denom,
    const unsigned short* __restrict__ At,
    const int* __restrict__ nperm, const int* __restrict__ toff,
    const int* __restrict__ mt_t, const int* __restrict__ mt_m,
    const int* __restrict__ gcnt,
    const float* __restrict__ skip, float* __restrict__ out) {
  int mtile = blockIdx.x;
  if (mtile >= gcnt[0]) return;
  int wave = threadIdx.x >> 6, lane = threadIdx.x & 63;
  int t = mt_t[mtile], tm = mt_m[mtile];
  int base = toff[t], cnt = toff[t + 1] - base;
  int lr = lane & 15, kq = lane >> 4;
  int arow = tm * 16 + lr;
  int prow = base + (arow < cnt ? arow : cnt - 1);
  float dn[4];
#pragma unroll
  for (int hh = 0; hh < 4; ++hh) {
    float d = denom[prow * 4 + hh];
    dn[hh] = d > 0.f ? 1.f / d : 0.f;
  }
  const unsigned short* g = aggh + (size_t)prow * 256 + kq * 8;
  bf16x8 af[8];
#pragma unroll
  for (int s = 0; s < 8; ++s) {
    bf16x8 x0 = *(const bf16x8*)(g + s * 32);
    bf16x8 x1 = *(const bf16x8*)(g + (size_t)NN * 256 + s * 32);
    bf16x8 x2 = *(const bf16x8*)(g + (size_t)2 * NN * 256 + s * 32);
    bf16x8 x3 = *(const bf16x8*)(g + (size_t)3 * NN * 256 + s * 32);
    float dv = dn[(kq * 8 + s * 32) >> 6];
#pragma unroll
    for (int m = 0; m < 8; ++m)
      af[s][m] = (short)f2bf((bf2f((unsigned short)x0[m]) + bf2f((unsigned short)x1[m]) +
                              bf2f((unsigned short)x2[m]) + bf2f((unsigned short)x3[m])) * dv);
  }
  int nd[4]; bool wr[4];
#pragma unroll
  for (int i = 0; i < 4; ++i) {
    int crow = tm * 16 + kq * 4 + i;
    wr[i] = crow < cnt;
    nd[i] = nperm[base + (wr[i] ? crow : 0)];
  }
  float sg = 1.f / (1.f + __expf(-skip[t]));
  for (int j = 0; j < 4; ++j) {
    int tn = wave * 4 + j;
    const unsigned short* bptr = At + (t * 256 + tn * 16 + lr) * 256 + kq * 8;
    f32x4 acc = {0.f, 0.f, 0.f, 0.f};
#pragma unroll
    for (int s = 0; s < 8; ++s)
      acc = mfma16(af[s], *(const bf16x8*)(bptr + s * 32), acc);
    int ccol = tn * 16 + lr;
#pragma unroll
    for (int i = 0; i < 4; ++i)
      if (wr[i]) out[nd[i] * 256 + ccol] = acc[i] * sg;
  }
}

extern "C" void kernel_launch(void* const* d_in, const int* in_sizes, int n_in,
                              void* d_out, int out_size, void* d_ws, size_t ws_size,
                              hipStream_t stream) {
  (void)in_sizes; (void)n_in; (void)out_size; (void)ws_size;
  const float* h    = (const float*)d_in[0];
  const float* Wk   = (const float*)d_in[1];
  const float* Wq   = (const float*)d_in[2];
  const float* Wv   = (const float*)d_in[3];
  const float* Wa   = (const float*)d_in[4];
  const float* ratt = (const float*)d_in[5];
  const float* rmsg = (const float*)d_in[6];
  const float* pri  = (const float*)d_in[7];
  const float* skp  = (const float*)d_in[8];
  const int* ntype  = (const int*)d_in[9];
  const int* etyp   = (const int*)d_in[10];
  const int* rowi   = (const int*)d_in[11];
  const int* coli   = (const int*)d_in[12];
  float* out = (float*)d_out;

  char* p = (char*)d_ws;
  auto alloc = [&](size_t bytes) {
    void* q = (void*)p;
    p += (bytes + 255) & ~(size_t)255;
    return q;
  };
  unsigned short* hbp  = (unsigned short*)alloc((size_t)NN * 256 * 2);
  unsigned short* Wt   = (unsigned short*)alloc((size_t)4 * 768 * 256 * 2);
  unsigned short* At   = (unsigned short*)alloc((size_t)4 * 256 * 256 * 2);
  unsigned short* Att  = (unsigned short*)alloc((size_t)32 * 4096 * 2);
  unsigned short* Mt   = (unsigned short*)alloc((size_t)32 * 4096 * 2);
  unsigned short* kvb  = (unsigned short*)alloc((size_t)NN * 512 * 2);
  unsigned short* qb   = (unsigned short*)alloc((size_t)NN * 256 * 2);
  unsigned short* aggh = (unsigned short*)alloc((size_t)4 * NN * 256 * 2);
  float* denom = (float*)alloc((size_t)NN * 4 * 4);
  int* toff  = (int*)alloc(32);
  int* ncur  = (int*)alloc(16);
  int* c4p   = (int*)alloc((size_t)CB * 4 * 4);
  int* nperm = (int*)alloc((size_t)NN * 4);
  int* inv   = (int*)alloc((size_t)NN * 4);
  int* bcnt  = (int*)alloc((size_t)NB * 4);
  int* boff  = (int*)alloc((size_t)(NB + 1) * 4);
  int* bcur  = (int*)alloc((size_t)NB * 4);
  int* psum  = (int*)alloc((size_t)625 * 4);
  int* je    = (int*)alloc((size_t)NE * 4);
  int* mt_t = (int*)alloc((size_t)1253 * 4);
  int* mt_m = (int*)alloc((size_t)1253 * 4);
  int* gcnt = (int*)alloc(32);

  // node buckets (perm space)
  k_tcount<<<CB, 256, 0, stream>>>(ntype, c4p);
  k_meta<<<1, 256, 0, stream>>>(c4p, toff, ncur, mt_t, mt_m, gcnt);
  k_nscatter<<<CB, 256, 0, stream>>>(ntype, ncur, nperm, inv);

  // fused prep (zero + h-cast-perm + weight transposes)
  k_prep_all<<<ZB + HB + WB + AB + RB, 256, 0, stream>>>(
      h, Wk, Wq, Wv, Wa, ratt, rmsg, nperm, bcnt, denom, hbp, Wt, At, Att, Mt);

  // edge CSR by (rel, perm-dst)
  k_bcount<<<(NE + 255) / 256, 256, 0, stream>>>(etyp, coli, inv, bcnt);
  k_scan1<<<625, 256, 0, stream>>>(bcnt, boff, psum);
  k_scan2<<<1, 1024, 0, stream>>>(psum);
  k_scan3<<<625, 256, 0, stream>>>(boff, bcur, psum);
  k_escatter<<<(NE + 255) / 256, 256, 0, stream>>>(etyp, rowi, coli, inv, bcur, je);

  // main pipeline
  k_gemm_kqv<<<1253, 256, 0, stream>>>(hbp, Wt, toff, mt_t, mt_m, gcnt, kvb, qb);
  k_mega<<<2500, 256, 0, stream>>>(boff, je, qb, kvb, Att, Mt, pri, aggh, denom);
  k_gemm_out<<<1253, 256, 0, stream>>>(aggh, denom, At, nperm, toff, mt_t, mt_m, gcnt,
                                       skp, out);
}

// Round 10
// 376.356 us; speedup vs baseline: 2.0744x; 1.0913x over previous
//
#include <hip/hip_runtime.h>

static constexpr int NN  = 20000;
static constexpr int NE  = 320000;
static constexpr int NTY = 4;
static constexpr int NRL = 8;
static constexpr int NB  = NRL * NN;   // 160000 bins = (rel, perm-dst)

// prep-kernel segment sizes (blocks of 256)
static constexpr int ZB = (NB + NN * 4 + 255) / 256;  // 938
static constexpr int WB = 4 * 768;                    // 3072
static constexpr int AB = 4 * 256;                    // 1024
static constexpr int RB = 32 * 4096 / 256;            // 512
static constexpr int CB = (NN + 255) / 256;           // 79 (type-count blocks)

typedef short bf16x8 __attribute__((ext_vector_type(8)));
typedef float f32x4  __attribute__((ext_vector_type(4)));
typedef unsigned short u16x4 __attribute__((ext_vector_type(4)));

__device__ __forceinline__ unsigned short f2bf(float f) {
  unsigned u = __float_as_uint(f);
  u += 0x7fffu + ((u >> 16) & 1u);
  return (unsigned short)(u >> 16);
}
__device__ __forceinline__ float bf2f(unsigned short b) {
  return __uint_as_float(((unsigned)b) << 16);
}
__device__ __forceinline__ f32x4 mfma16(bf16x8 a, bf16x8 b, f32x4 c) {
  return __builtin_amdgcn_mfma_f32_16x16x32_bf16(a, b, c, 0, 0, 0);
}

// ---------------- node-type counting (parallel partials) ----------------
__global__ void k_tcount(const int* __restrict__ ntype, int* __restrict__ c4p) {
  __shared__ int c[4];
  if (threadIdx.x < 4) c[threadIdx.x] = 0;
  __syncthreads();
  int i = blockIdx.x * 256 + threadIdx.x;
  if (i < NN) atomicAdd(&c[ntype[i]], 1);
  __syncthreads();
  if (threadIdx.x < 4) c4p[blockIdx.x * 4 + threadIdx.x] = c[threadIdx.x];
}
// meta: type offsets + 64-row tile list
__global__ void k_meta(const int* __restrict__ c4p, int* toff, int* ncur,
                       int* mt64_t, int* mt64_m, int* gcnt) {
  __shared__ int c4[4];
  __shared__ int ts[5];
  if (threadIdx.x < 4) {
    int s = 0;
    for (int b = 0; b < CB; ++b) s += c4p[b * 4 + threadIdx.x];
    c4[threadIdx.x] = s;
  }
  __syncthreads();
  if (threadIdx.x == 0) {
    int s = 0, s2 = 0;
    for (int t = 0; t < NTY; ++t) {
      toff[t] = s; ncur[t] = s; s += c4[t];
      ts[t] = s2; s2 += (c4[t] + 63) >> 6;
    }
    toff[NTY] = s; ts[NTY] = s2; gcnt[0] = s2;
  }
  __syncthreads();
  int n64 = ts[4];
  for (int i = threadIdx.x; i < n64; i += 256) {
    int t = 0;
    while (t < 3 && i >= ts[t + 1]) ++t;
    mt64_t[i] = t; mt64_m[i] = i - ts[t];
  }
}
__global__ void k_nscatter(const int* __restrict__ key, int* cur,
                           int* nperm, int* inv) {
  int i = blockIdx.x * 256 + threadIdx.x;
  if (i < NN) {
    int p = atomicAdd(&cur[key[i]], 1);
    nperm[p] = i;
    inv[i] = p;
  }
}

// ---------------- fused prep: zero + weight transposes ----------------
__global__ void k_prep_all(const float* __restrict__ Wk,
                           const float* __restrict__ Wq, const float* __restrict__ Wv,
                           const float* __restrict__ Wa, const float* __restrict__ ratt,
                           const float* __restrict__ rmsg,
                           int* bcnt, float* denom,
                           unsigned short* Wt, unsigned short* At,
                           unsigned short* Att, unsigned short* Mt) {
  int b = blockIdx.x;
  if (b < ZB) {
    int i = b * 256 + threadIdx.x;
    if (i < NB) bcnt[i] = 0;
    else if (i < NB + NN * 4) denom[i - NB] = 0.f;
  } else if (b < ZB + WB) {
    int bb = b - ZB;
    int j = bb % 768, t = bb / 768, i = threadIdx.x;
    const float* src; int c;
    if (j < 256)      { src = Wk; c = j; }
    else if (j < 512) { src = Wq; c = j - 256; }
    else              { src = Wv; c = j - 512; }
    Wt[(t * 768 + j) * 256 + i] = f2bf(src[(t * 256 + i) * 256 + c]);
  } else if (b < ZB + WB + AB) {
    int bb = b - (ZB + WB);
    int j = bb % 256, t = bb / 256, i = threadIdx.x;
    At[(t * 256 + j) * 256 + i] = f2bf(Wa[(t * 256 + i) * 256 + j]);
  } else {
    int idx = (b - (ZB + WB + AB)) * 256 + threadIdx.x;
    int rh = idx >> 12, e = (idx >> 6) & 63, d = idx & 63;
    Att[idx] = f2bf(ratt[rh * 4096 + d * 64 + e]);
    Mt[idx]  = f2bf(rmsg[rh * 4096 + d * 64 + e]);
  }
}

// ---------------- edge CSR by (rel, perm-dst) ----------------
__global__ void k_bcount(const int* __restrict__ etyp, const int* __restrict__ coli,
                         const int* __restrict__ inv, int* bcnt) {
  int e = blockIdx.x * 256 + threadIdx.x;
  if (e < NE) atomicAdd(&bcnt[etyp[e] * NN + inv[coli[e]]], 1);
}
__global__ void k_scan1(const int* cnt, int* off, int* psum) {
  __shared__ int sm[256];
  int i = blockIdx.x * 256 + threadIdx.x;
  int v = cnt[i];
  sm[threadIdx.x] = v;
  __syncthreads();
  for (int d = 1; d < 256; d <<= 1) {
    int t = (threadIdx.x >= d) ? sm[threadIdx.x - d] : 0;
    __syncthreads();
    sm[threadIdx.x] += t;
    __syncthreads();
  }
  off[i] = sm[threadIdx.x] - v;
  if (threadIdx.x == 255) psum[blockIdx.x] = sm[255];
}
__global__ void k_scan2(int* psum) {
  __shared__ int sm[1024];
  int t = threadIdx.x;
  int v = (t < 625) ? psum[t] : 0;
  sm[t] = v;
  __syncthreads();
  for (int d = 1; d < 1024; d <<= 1) {
    int x = (t >= d) ? sm[t - d] : 0;
    __syncthreads();
    sm[t] += x;
    __syncthreads();
  }
  if (t < 625) psum[t] = sm[t] - v;
}
__global__ void k_scan3(int* off, int* cur, const int* psum) {
  int i = blockIdx.x * 256 + threadIdx.x;
  int v = off[i] + psum[blockIdx.x];
  off[i] = v; cur[i] = v;
  if (i == 0) off[NB] = NE;
}
__global__ void k_escatter(const int* __restrict__ etyp, const int* __restrict__ rowi,
                           const int* __restrict__ coli, const int* __restrict__ inv,
                           int* cur, int* je) {
  int e = blockIdx.x * 256 + threadIdx.x;
  if (e >= NE) return;
  int bin = etyp[e] * NN + inv[coli[e]];
  int j = atomicAdd(&cur[bin], 1);
  je[j] = inv[rowi[e]];
}

// ---------------- K1: typed K/Q/V projection, 64-row blocks, LDS-staged B -----------
__global__ __launch_bounds__(256) void k_gemm_kqv(
    const float* __restrict__ hsrc, const unsigned short* __restrict__ Wt,
    const int* __restrict__ nperm, const int* __restrict__ toff,
    const int* __restrict__ mt64_t, const int* __restrict__ mt64_m,
    const int* __restrict__ gcnt,
    unsigned short* __restrict__ kvb, unsigned short* __restrict__ qb) {
  __shared__ unsigned short bs[16][264];
  int mtile = blockIdx.x;
  if (mtile >= gcnt[0]) return;
  int wave = threadIdx.x >> 6, lane = threadIdx.x & 63;
  int t = mt64_t[mtile], tm = mt64_m[mtile];
  int base = toff[t], cnt = toff[t + 1] - base;
  int lr = lane & 15, kq = lane >> 4;
  int arow = tm * 64 + wave * 16 + lr;
  int prow = base + (arow < cnt ? arow : cnt - 1);
  int node = nperm[prow];
  const float* ap = hsrc + (size_t)node * 256 + kq * 8;
  bf16x8 af[8];
#pragma unroll
  for (int s = 0; s < 8; ++s) {
    f32x4 x0 = *(const f32x4*)(ap + s * 32);
    f32x4 x1 = *(const f32x4*)(ap + s * 32 + 4);
    bf16x8 o;
    o[0] = (short)f2bf(x0[0]); o[1] = (short)f2bf(x0[1]);
    o[2] = (short)f2bf(x0[2]); o[3] = (short)f2bf(x0[3]);
    o[4] = (short)f2bf(x1[0]); o[5] = (short)f2bf(x1[1]);
    o[6] = (short)f2bf(x1[2]); o[7] = (short)f2bf(x1[3]);
    af[s] = o;
  }
  int pr[4]; bool wr[4];
#pragma unroll
  for (int i = 0; i < 4; ++i) {
    int crow = tm * 64 + wave * 16 + kq * 4 + i;
    wr[i] = crow < cnt;
    pr[i] = base + (wr[i] ? crow : 0);
  }
  int sc = threadIdx.x >> 4;     // staging col 0..15
  int seg = threadIdx.x & 15;    // staging 16-short segment
  for (int tn = 0; tn < 48; ++tn) {
    const unsigned short* wsrc = Wt + ((size_t)(t * 768 + tn * 16 + sc)) * 256 + seg * 16;
    __syncthreads();
    *(bf16x8*)&bs[sc][seg * 16]     = *(const bf16x8*)wsrc;
    *(bf16x8*)&bs[sc][seg * 16 + 8] = *(const bf16x8*)(wsrc + 8);
    __syncthreads();
    f32x4 acc = {0.f, 0.f, 0.f, 0.f};
#pragma unroll
    for (int s = 0; s < 8; ++s)
      acc = mfma16(af[s], *(const bf16x8*)&bs[lr][kq * 8 + s * 32], acc);
    int ccol = tn * 16 + lr;
#pragma unroll
    for (int i = 0; i < 4; ++i) {
      if (wr[i]) {
        unsigned short v = f2bf(acc[i]);
        if (ccol < 256)
          kvb[(size_t)pr[i] * 512 + (ccol >> 6) * 128 + (ccol & 63)] = v;
        else if (ccol < 512)
          qb[(size_t)pr[i] * 256 + (ccol - 256)] = v;
        else {
          int c = ccol - 512;
          kvb[(size_t)pr[i] * 512 + (c >> 6) * 128 + 64 + (c & 63)] = v;
        }
      }
    }
  }
}

// ---------------- K2: mega — 32 bins/wave, bf16 LDS, packed-bf16 qt -----------------
// block = (dst-tile of 32, relation-quarter = 2 rels); wave = head.
__global__ __launch_bounds__(256) void k_mega(
    const int* __restrict__ boff, const int* __restrict__ je,
    const unsigned short* __restrict__ qb, const unsigned short* __restrict__ kvb,
    const unsigned short* __restrict__ Att, const unsigned short* __restrict__ Mt,
    const float* __restrict__ pri, unsigned short* __restrict__ aggh,
    float* __restrict__ denom) {
  __shared__ unsigned short qsh[4][32][80];   // bf16 [head][dst_local][dim], stride 80
  int dt = blockIdx.x >> 2, quarter = blockIdx.x & 3;
  int h = threadIdx.x >> 6, lane = threadIdx.x & 63;
  int lr16 = lane & 15, kq4 = lane >> 4;    // MFMA mapping
  int lr32 = lane & 31, kq1 = lane >> 5;    // edge-loop mapping
  int r0 = quarter * 2;
  float dtot = 0.f;
  f32x4 C[2][4] = {{{0.f,0.f,0.f,0.f},{0.f,0.f,0.f,0.f},{0.f,0.f,0.f,0.f},{0.f,0.f,0.f,0.f}},
                   {{0.f,0.f,0.f,0.f},{0.f,0.f,0.f,0.f},{0.f,0.f,0.f,0.f},{0.f,0.f,0.f,0.f}}};
  for (int rr = 0; rr < 2; ++rr) {
    int r = r0 + rr;
    int rh = r * 4 + h;
    int bin = r * NN + dt * 32 + lr32;
    int b0 = boff[bin], b1 = boff[bin + 1];
    // ---- phase 1: qt = q @ A_r^T via MFMA (two 16-row halves) -> qsh bf16 ----
#pragma unroll
    for (int hf = 0; hf < 2; ++hf) {
      const unsigned short* ap = qb + (size_t)(dt * 32 + hf * 16 + lr16) * 256 + h * 64 + kq4 * 8;
      bf16x8 aq0 = *(const bf16x8*)ap;
      bf16x8 aq1 = *(const bf16x8*)(ap + 32);
#pragma unroll
      for (int tn = 0; tn < 4; ++tn) {
        const unsigned short* bp = Att + ((rh * 64 + tn * 16 + lr16) * 64) + kq4 * 8;
        f32x4 a = {0.f, 0.f, 0.f, 0.f};
        a = mfma16(aq0, *(const bf16x8*)bp, a);
        a = mfma16(aq1, *(const bf16x8*)(bp + 32), a);
#pragma unroll
        for (int i = 0; i < 4; ++i)
          qsh[h][hf * 16 + kq4 * 4 + i][tn * 16 + lr16] = f2bf(a[i]);
      }
    }
    // ---- qt -> packed bf16 registers (wave-local LDS round trip) ----
    bf16x8 qtp[4];
#pragma unroll
    for (int g = 0; g < 4; ++g)
      qtp[g] = *(const bf16x8*)&qsh[h][lr32][kq1 * 32 + g * 8];
    // ---- phase 2: per-lane bin walk; lane owns (bin lr32, dim half kq1) ----
    float acc[32];
#pragma unroll
    for (int m = 0; m < 32; ++m) acc[m] = 0.f;
    float prs = pri[rh] * 0.125f;
    for (int j = b0; j < b1; ++j) {
      int src = je[j];
      const unsigned short* kp = kvb + (size_t)src * 512 + h * 128 + kq1 * 32;
      bf16x8 k0 = *(const bf16x8*)kp;
      bf16x8 k1 = *(const bf16x8*)(kp + 8);
      bf16x8 k2 = *(const bf16x8*)(kp + 16);
      bf16x8 k3 = *(const bf16x8*)(kp + 24);
      bf16x8 v0 = *(const bf16x8*)(kp + 64);
      bf16x8 v1 = *(const bf16x8*)(kp + 72);
      bf16x8 v2 = *(const bf16x8*)(kp + 80);
      bf16x8 v3 = *(const bf16x8*)(kp + 88);
      float s = 0.f;
#pragma unroll
      for (int m = 0; m < 8; ++m) {
        s += bf2f((unsigned short)qtp[0][m]) * bf2f((unsigned short)k0[m]);
        s += bf2f((unsigned short)qtp[1][m]) * bf2f((unsigned short)k1[m]);
        s += bf2f((unsigned short)qtp[2][m]) * bf2f((unsigned short)k2[m]);
        s += bf2f((unsigned short)qtp[3][m]) * bf2f((unsigned short)k3[m]);
      }
      s += __shfl_xor(s, 32);
      float ex = __expf(s * prs);
      dtot += ex;
#pragma unroll
      for (int m = 0; m < 8; ++m) {
        acc[m]      += ex * bf2f((unsigned short)v0[m]);
        acc[8 + m]  += ex * bf2f((unsigned short)v1[m]);
        acc[16 + m] += ex * bf2f((unsigned short)v2[m]);
        acc[24 + m] += ex * bf2f((unsigned short)v3[m]);
      }
    }
    // ---- phase 3: stage acc -> qsh as bf16, M-transform via MFMA ----
#pragma unroll
    for (int g = 0; g < 4; ++g) {
      bf16x8 o;
#pragma unroll
      for (int m = 0; m < 8; ++m) o[m] = (short)f2bf(acc[g * 8 + m]);
      *(bf16x8*)&qsh[h][lr32][kq1 * 32 + g * 8] = o;
    }
#pragma unroll
    for (int hf = 0; hf < 2; ++hf) {
      bf16x8 m0 = *(const bf16x8*)&qsh[h][hf * 16 + lr16][kq4 * 8];
      bf16x8 m1 = *(const bf16x8*)&qsh[h][hf * 16 + lr16][32 + kq4 * 8];
#pragma unroll
      for (int tn = 0; tn < 4; ++tn) {
        const unsigned short* bp = Mt + ((rh * 64 + tn * 16 + lr16) * 64) + kq4 * 8;
        C[hf][tn] = mfma16(m0, *(const bf16x8*)bp, C[hf][tn]);
        C[hf][tn] = mfma16(m1, *(const bf16x8*)(bp + 32), C[hf][tn]);
      }
    }
  }
  if (kq1 == 0) atomicAdd(&denom[(dt * 32 + lr32) * 4 + h], dtot);
#pragma unroll
  for (int hf = 0; hf < 2; ++hf)
#pragma unroll
    for (int tn = 0; tn < 4; ++tn)
#pragma unroll
      for (int i = 0; i < 4; ++i)
        aggh[((size_t)quarter * NN + dt * 32 + hf * 16 + kq4 * 4 + i) * 256 +
             h * 64 + tn * 16 + lr16] = f2bf(C[hf][tn][i]);
}

// ---------------- K3: final projection, 64-row blocks, LDS-staged B -----------------
__global__ __launch_bounds__(256) void k_gemm_out(
    const unsigned short* __restrict__ aggh, const float* __restrict__ denom,
    const unsigned short* __restrict__ At,
    const int* __restrict__ nperm, const int* __restrict__ toff,
    const int* __restrict__ mt64_t, const int* __restrict__ mt64_m,
    const int* __restrict__ gcnt,
    const float* __restrict__ skip, float* __restrict__ out) {
  __shared__ unsigned short bs[16][264];
  int mtile = blockIdx.x;
  if (mtile >= gcnt[0]) return;
  int wave = threadIdx.x >> 6, lane = threadIdx.x & 63;
  int t = mt64_t[mtile], tm = mt64_m[mtile];
  int base = toff[t], cnt = toff[t + 1] - base;
  int lr = lane & 15, kq = lane >> 4;
  int arow = tm * 64 + wave * 16 + lr;
  int prow = base + (arow < cnt ? arow : cnt - 1);
  float dn[4];
#pragma unroll
  for (int hh = 0; hh < 4; ++hh) {
    float d = denom[prow * 4 + hh];
    dn[hh] = d > 0.f ? 1.f / d : 0.f;
  }
  const unsigned short* g = aggh + (size_t)prow * 256 + kq * 8;
  bf16x8 af[8];
#pragma unroll
  for (int s = 0; s < 8; ++s) {
    bf16x8 x0 = *(const bf16x8*)(g + s * 32);
    bf16x8 x1 = *(const bf16x8*)(g + (size_t)NN * 256 + s * 32);
    bf16x8 x2 = *(const bf16x8*)(g + (size_t)2 * NN * 256 + s * 32);
    bf16x8 x3 = *(const bf16x8*)(g + (size_t)3 * NN * 256 + s * 32);
    float dv = dn[(kq * 8 + s * 32) >> 6];
#pragma unroll
    for (int m = 0; m < 8; ++m)
      af[s][m] = (short)f2bf((bf2f((unsigned short)x0[m]) + bf2f((unsigned short)x1[m]) +
                              bf2f((unsigned short)x2[m]) + bf2f((unsigned short)x3[m])) * dv);
  }
  int nd[4]; bool wr[4];
#pragma unroll
  for (int i = 0; i < 4; ++i) {
    int crow = tm * 64 + wave * 16 + kq * 4 + i;
    wr[i] = crow < cnt;
    nd[i] = nperm[base + (wr[i] ? crow : 0)];
  }
  float sg = 1.f / (1.f + __expf(-skip[t]));
  int sc = threadIdx.x >> 4;
  int seg = threadIdx.x & 15;
  for (int tn = 0; tn < 16; ++tn) {
    const unsigned short* wsrc = At + ((size_t)(t * 256 + tn * 16 + sc)) * 256 + seg * 16;
    __syncthreads();
    *(bf16x8*)&bs[sc][seg * 16]     = *(const bf16x8*)wsrc;
    *(bf16x8*)&bs[sc][seg * 16 + 8] = *(const bf16x8*)(wsrc + 8);
    __syncthreads();
    f32x4 acc = {0.f, 0.f, 0.f, 0.f};
#pragma unroll
    for (int s = 0; s < 8; ++s)
      acc = mfma16(af[s], *(const bf16x8*)&bs[lr][kq * 8 + s * 32], acc);
    int ccol = tn * 16 + lr;
#pragma unroll
    for (int i = 0; i < 4; ++i)
      if (wr[i]) out[nd[i] * 256 + ccol] = acc[i] * sg;
  }
}

extern "C" void kernel_launch(void* const* d_in, const int* in_sizes, int n_in,
                              void* d_out, int out_size, void* d_ws, size_t ws_size,
                              hipStream_t stream) {
  (void)in_sizes; (void)n_in; (void)out_size; (void)ws_size;
  const float* h    = (const float*)d_in[0];
  const float* Wk   = (const float*)d_in[1];
  const float* Wq   = (const float*)d_in[2];
  const float* Wv   = (const float*)d_in[3];
  const float* Wa   = (const float*)d_in[4];
  const float* ratt = (const float*)d_in[5];
  const float* rmsg = (const float*)d_in[6];
  const float* pri  = (const float*)d_in[7];
  const float* skp  = (const float*)d_in[8];
  const int* ntype  = (const int*)d_in[9];
  const int* etyp   = (const int*)d_in[10];
  const int* rowi   = (const int*)d_in[11];
  const int* coli   = (const int*)d_in[12];
  float* out = (float*)d_out;

  char* p = (char*)d_ws;
  auto alloc = [&](size_t bytes) {
    void* q = (void*)p;
    p += (bytes + 255) & ~(size_t)255;
    return q;
  };
  unsigned short* Wt   = (unsigned short*)alloc((size_t)4 * 768 * 256 * 2);
  unsigned short* At   = (unsigned short*)alloc((size_t)4 * 256 * 256 * 2);
  unsigned short* Att  = (unsigned short*)alloc((size_t)32 * 4096 * 2);
  unsigned short* Mt   = (unsigned short*)alloc((size_t)32 * 4096 * 2);
  unsigned short* kvb  = (unsigned short*)alloc((size_t)NN * 512 * 2);
  unsigned short* qb   = (unsigned short*)alloc((size_t)NN * 256 * 2);
  unsigned short* aggh = (unsigned short*)alloc((size_t)4 * NN * 256 * 2);
  float* denom = (float*)alloc((size_t)NN * 4 * 4);
  int* toff   = (int*)alloc(32);
  int* ncur   = (int*)alloc(16);
  int* c4p    = (int*)alloc((size_t)CB * 4 * 4);
  int* nperm  = (int*)alloc((size_t)NN * 4);
  int* inv    = (int*)alloc((size_t)NN * 4);
  int* bcnt   = (int*)alloc((size_t)NB * 4);
  int* boff   = (int*)alloc((size_t)(NB + 1) * 4);
  int* bcur   = (int*)alloc((size_t)NB * 4);
  int* psum   = (int*)alloc((size_t)625 * 4);
  int* je     = (int*)alloc((size_t)NE * 4);
  int* mt64_t = (int*)alloc((size_t)324 * 4);
  int* mt64_m = (int*)alloc((size_t)324 * 4);
  int* gcnt   = (int*)alloc(32);

  // node buckets (perm space)
  k_tcount<<<CB, 256, 0, stream>>>(ntype, c4p);
  k_meta<<<1, 256, 0, stream>>>(c4p, toff, ncur, mt64_t, mt64_m, gcnt);
  k_nscatter<<<CB, 256, 0, stream>>>(ntype, ncur, nperm, inv);

  // fused prep (zero + weight transposes)
  k_prep_all<<<ZB + WB + AB + RB, 256, 0, stream>>>(
      Wk, Wq, Wv, Wa, ratt, rmsg, bcnt, denom, Wt, At, Att, Mt);

  // edge CSR by (rel, perm-dst)
  k_bcount<<<(NE + 255) / 256, 256, 0, stream>>>(etyp, coli, inv, bcnt);
  k_scan1<<<625, 256, 0, stream>>>(bcnt, boff, psum);
  k_scan2<<<1, 1024, 0, stream>>>(psum);
  k_scan3<<<625, 256, 0, stream>>>(boff, bcur, psum);
  k_escatter<<<(NE + 255) / 256, 256, 0, stream>>>(etyp, rowi, coli, inv, bcur, je);

  // main pipeline
  k_gemm_kqv<<<320, 256, 0, stream>>>(h, Wt, nperm, toff, mt64_t, mt64_m, gcnt, kvb, qb);
  k_mega<<<2500, 256, 0, stream>>>(boff, je, qb, kvb, Att, Mt, pri, aggh, denom);
  k_gemm_out<<<320, 256, 0, stream>>>(aggh, denom, At, nperm, toff, mt64_t, mt64_m, gcnt,
                                      skp, out);
}

// Round 11
// 337.240 us; speedup vs baseline: 2.3150x; 1.1160x over previous
//
#include <hip/hip_runtime.h>

static constexpr int NN  = 20000;
static constexpr int NE  = 320000;
static constexpr int NTY = 4;
static constexpr int NRL = 8;
static constexpr int NB  = NRL * NN;   // 160000 bins = (rel, perm-dst)

// prep-kernel segment sizes (blocks of 256)
static constexpr int ZB = (NB + NN * 4 + 255) / 256;  // 938
static constexpr int WB = 4 * 768;                    // 3072
static constexpr int AB = 4 * 256;                    // 1024
static constexpr int RB = 32 * 4096 / 256;            // 512
static constexpr int CB = (NN + 255) / 256;           // 79 (type-count blocks)

typedef short bf16x8 __attribute__((ext_vector_type(8)));
typedef float f32x4  __attribute__((ext_vector_type(4)));
typedef unsigned short u16x4 __attribute__((ext_vector_type(4)));

__device__ __forceinline__ unsigned short f2bf(float f) {
  unsigned u = __float_as_uint(f);
  u += 0x7fffu + ((u >> 16) & 1u);
  return (unsigned short)(u >> 16);
}
__device__ __forceinline__ float bf2f(unsigned short b) {
  return __uint_as_float(((unsigned)b) << 16);
}
__device__ __forceinline__ f32x4 mfma16(bf16x8 a, bf16x8 b, f32x4 c) {
  return __builtin_amdgcn_mfma_f32_16x16x32_bf16(a, b, c, 0, 0, 0);
}

// ---------------- node-type counting (parallel partials) ----------------
__global__ void k_tcount(const int* __restrict__ ntype, int* __restrict__ c4p) {
  __shared__ int c[4];
  if (threadIdx.x < 4) c[threadIdx.x] = 0;
  __syncthreads();
  int i = blockIdx.x * 256 + threadIdx.x;
  if (i < NN) atomicAdd(&c[ntype[i]], 1);
  __syncthreads();
  if (threadIdx.x < 4) c4p[blockIdx.x * 4 + threadIdx.x] = c[threadIdx.x];
}
// meta: type offsets + 64-row tile list
__global__ void k_meta(const int* __restrict__ c4p, int* toff, int* ncur,
                       int* mt64_t, int* mt64_m, int* gcnt) {
  __shared__ int c4[4];
  __shared__ int ts[5];
  if (threadIdx.x < 4) {
    int s = 0;
    for (int b = 0; b < CB; ++b) s += c4p[b * 4 + threadIdx.x];
    c4[threadIdx.x] = s;
  }
  __syncthreads();
  if (threadIdx.x == 0) {
    int s = 0, s2 = 0;
    for (int t = 0; t < NTY; ++t) {
      toff[t] = s; ncur[t] = s; s += c4[t];
      ts[t] = s2; s2 += (c4[t] + 63) >> 6;
    }
    toff[NTY] = s; ts[NTY] = s2; gcnt[0] = s2;
  }
  __syncthreads();
  int n64 = ts[4];
  for (int i = threadIdx.x; i < n64; i += 256) {
    int t = 0;
    while (t < 3 && i >= ts[t + 1]) ++t;
    mt64_t[i] = t; mt64_m[i] = i - ts[t];
  }
}
__global__ void k_nscatter(const int* __restrict__ key, int* cur,
                           int* nperm, int* inv) {
  int i = blockIdx.x * 256 + threadIdx.x;
  if (i < NN) {
    int p = atomicAdd(&cur[key[i]], 1);
    nperm[p] = i;
    inv[i] = p;
  }
}

// ---------------- fused prep: zero + weight transposes ----------------
__global__ void k_prep_all(const float* __restrict__ Wk,
                           const float* __restrict__ Wq, const float* __restrict__ Wv,
                           const float* __restrict__ Wa, const float* __restrict__ ratt,
                           const float* __restrict__ rmsg,
                           int* bcnt, float* denom,
                           unsigned short* Wt, unsigned short* At,
                           unsigned short* Att, unsigned short* Mt) {
  int b = blockIdx.x;
  if (b < ZB) {
    int i = b * 256 + threadIdx.x;
    if (i < NB) bcnt[i] = 0;
    else if (i < NB + NN * 4) denom[i - NB] = 0.f;
  } else if (b < ZB + WB) {
    int bb = b - ZB;
    int j = bb % 768, t = bb / 768, i = threadIdx.x;
    const float* src; int c;
    if (j < 256)      { src = Wk; c = j; }
    else if (j < 512) { src = Wq; c = j - 256; }
    else              { src = Wv; c = j - 512; }
    Wt[(t * 768 + j) * 256 + i] = f2bf(src[(t * 256 + i) * 256 + c]);
  } else if (b < ZB + WB + AB) {
    int bb = b - (ZB + WB);
    int j = bb % 256, t = bb / 256, i = threadIdx.x;
    At[(t * 256 + j) * 256 + i] = f2bf(Wa[(t * 256 + i) * 256 + j]);
  } else {
    int idx = (b - (ZB + WB + AB)) * 256 + threadIdx.x;
    int rh = idx >> 12, e = (idx >> 6) & 63, d = idx & 63;
    Att[idx] = f2bf(ratt[rh * 4096 + d * 64 + e]);
    Mt[idx]  = f2bf(rmsg[rh * 4096 + d * 64 + e]);
  }
}

// ---------------- edge CSR by (rel, perm-dst) ----------------
__global__ void k_bcount(const int* __restrict__ etyp, const int* __restrict__ coli,
                         const int* __restrict__ inv, int* bcnt) {
  int e = blockIdx.x * 256 + threadIdx.x;
  if (e < NE) atomicAdd(&bcnt[etyp[e] * NN + inv[coli[e]]], 1);
}
__global__ void k_scan1(const int* cnt, int* off, int* psum) {
  __shared__ int sm[256];
  int i = blockIdx.x * 256 + threadIdx.x;
  int v = cnt[i];
  sm[threadIdx.x] = v;
  __syncthreads();
  for (int d = 1; d < 256; d <<= 1) {
    int t = (threadIdx.x >= d) ? sm[threadIdx.x - d] : 0;
    __syncthreads();
    sm[threadIdx.x] += t;
    __syncthreads();
  }
  off[i] = sm[threadIdx.x] - v;
  if (threadIdx.x == 255) psum[blockIdx.x] = sm[255];
}
__global__ void k_scan2(int* psum) {
  __shared__ int sm[1024];
  int t = threadIdx.x;
  int v = (t < 625) ? psum[t] : 0;
  sm[t] = v;
  __syncthreads();
  for (int d = 1; d < 1024; d <<= 1) {
    int x = (t >= d) ? sm[t - d] : 0;
    __syncthreads();
    sm[t] += x;
    __syncthreads();
  }
  if (t < 625) psum[t] = sm[t] - v;
}
__global__ void k_scan3(int* off, int* cur, const int* psum) {
  int i = blockIdx.x * 256 + threadIdx.x;
  int v = off[i] + psum[blockIdx.x];
  off[i] = v; cur[i] = v;
  if (i == 0) off[NB] = NE;
}
__global__ void k_escatter(const int* __restrict__ etyp, const int* __restrict__ rowi,
                           const int* __restrict__ coli, const int* __restrict__ inv,
                           int* cur, int* je) {
  int e = blockIdx.x * 256 + threadIdx.x;
  if (e >= NE) return;
  int bin = etyp[e] * NN + inv[coli[e]];
  int j = atomicAdd(&cur[bin], 1);
  je[j] = inv[rowi[e]];
}

// ---------------- K1: typed K/Q/V projection, 64-row x 16-col-tile blocks ------------
// blockIdx.x = mtile*3 + chunk; each block does 16 of 48 col tiles (B traffic unchanged,
// 3x concurrency vs monolithic 48-tile blocks).
__global__ __launch_bounds__(256) void k_gemm_kqv(
    const float* __restrict__ hsrc, const unsigned short* __restrict__ Wt,
    const int* __restrict__ nperm, const int* __restrict__ toff,
    const int* __restrict__ mt64_t, const int* __restrict__ mt64_m,
    const int* __restrict__ gcnt,
    unsigned short* __restrict__ kvb, unsigned short* __restrict__ qb) {
  __shared__ unsigned short bs[16][264];
  int mtile = blockIdx.x / 3, chunk = blockIdx.x % 3;
  if (mtile >= gcnt[0]) return;
  int wave = threadIdx.x >> 6, lane = threadIdx.x & 63;
  int t = mt64_t[mtile], tm = mt64_m[mtile];
  int base = toff[t], cnt = toff[t + 1] - base;
  int lr = lane & 15, kq = lane >> 4;
  int arow = tm * 64 + wave * 16 + lr;
  int prow = base + (arow < cnt ? arow : cnt - 1);
  int node = nperm[prow];
  const float* ap = hsrc + (size_t)node * 256 + kq * 8;
  bf16x8 af[8];
#pragma unroll
  for (int s = 0; s < 8; ++s) {
    f32x4 x0 = *(const f32x4*)(ap + s * 32);
    f32x4 x1 = *(const f32x4*)(ap + s * 32 + 4);
    bf16x8 o;
    o[0] = (short)f2bf(x0[0]); o[1] = (short)f2bf(x0[1]);
    o[2] = (short)f2bf(x0[2]); o[3] = (short)f2bf(x0[3]);
    o[4] = (short)f2bf(x1[0]); o[5] = (short)f2bf(x1[1]);
    o[6] = (short)f2bf(x1[2]); o[7] = (short)f2bf(x1[3]);
    af[s] = o;
  }
  int pr[4]; bool wr[4];
#pragma unroll
  for (int i = 0; i < 4; ++i) {
    int crow = tm * 64 + wave * 16 + kq * 4 + i;
    wr[i] = crow < cnt;
    pr[i] = base + (wr[i] ? crow : 0);
  }
  int sc = threadIdx.x >> 4;     // staging col 0..15
  int seg = threadIdx.x & 15;    // staging 16-short segment
  for (int tt = 0; tt < 16; ++tt) {
    int tn = chunk * 16 + tt;
    const unsigned short* wsrc = Wt + ((size_t)(t * 768 + tn * 16 + sc)) * 256 + seg * 16;
    __syncthreads();
    *(bf16x8*)&bs[sc][seg * 16]     = *(const bf16x8*)wsrc;
    *(bf16x8*)&bs[sc][seg * 16 + 8] = *(const bf16x8*)(wsrc + 8);
    __syncthreads();
    f32x4 acc = {0.f, 0.f, 0.f, 0.f};
#pragma unroll
    for (int s = 0; s < 8; ++s)
      acc = mfma16(af[s], *(const bf16x8*)&bs[lr][kq * 8 + s * 32], acc);
    int ccol = tn * 16 + lr;
#pragma unroll
    for (int i = 0; i < 4; ++i) {
      if (wr[i]) {
        unsigned short v = f2bf(acc[i]);
        if (ccol < 256)
          kvb[(size_t)pr[i] * 512 + (ccol >> 6) * 128 + (ccol & 63)] = v;
        else if (ccol < 512)
          qb[(size_t)pr[i] * 256 + (ccol - 256)] = v;
        else {
          int c = ccol - 512;
          kvb[(size_t)pr[i] * 512 + (c >> 6) * 128 + 64 + (c & 63)] = v;
        }
      }
    }
  }
}

// ---------------- K2: mega — 32 bins/wave, f32 LDS (R9 body) + je prefetch ----------
// block = (dst-tile of 32, relation-quarter = 2 rels); wave = head.
__global__ __launch_bounds__(256) void k_mega(
    const int* __restrict__ boff, const int* __restrict__ je,
    const unsigned short* __restrict__ qb, const unsigned short* __restrict__ kvb,
    const unsigned short* __restrict__ Att, const unsigned short* __restrict__ Mt,
    const float* __restrict__ pri, unsigned short* __restrict__ aggh,
    float* __restrict__ denom) {
  __shared__ float qsh[4][32][68];   // [head][dst_local][dim] f32, stride 68
  int dt = blockIdx.x >> 2, quarter = blockIdx.x & 3;
  int h = threadIdx.x >> 6, lane = threadIdx.x & 63;
  int lr16 = lane & 15, kq4 = lane >> 4;    // MFMA mapping
  int lr32 = lane & 31, kq1 = lane >> 5;    // edge-loop mapping
  int r0 = quarter * 2;
  float dtot = 0.f;
  f32x4 C[2][4] = {{{0.f,0.f,0.f,0.f},{0.f,0.f,0.f,0.f},{0.f,0.f,0.f,0.f},{0.f,0.f,0.f,0.f}},
                   {{0.f,0.f,0.f,0.f},{0.f,0.f,0.f,0.f},{0.f,0.f,0.f,0.f},{0.f,0.f,0.f,0.f}}};
  for (int rr = 0; rr < 2; ++rr) {
    int r = r0 + rr;
    int rh = r * 4 + h;
    int bin = r * NN + dt * 32 + lr32;
    int b0 = boff[bin], b1 = boff[bin + 1];
    // ---- phase 1: qt = q @ A_r^T via MFMA (two 16-row halves) -> qsh f32 ----
#pragma unroll
    for (int hf = 0; hf < 2; ++hf) {
      const unsigned short* ap = qb + (size_t)(dt * 32 + hf * 16 + lr16) * 256 + h * 64 + kq4 * 8;
      bf16x8 aq0 = *(const bf16x8*)ap;
      bf16x8 aq1 = *(const bf16x8*)(ap + 32);
#pragma unroll
      for (int tn = 0; tn < 4; ++tn) {
        const unsigned short* bp = Att + ((rh * 64 + tn * 16 + lr16) * 64) + kq4 * 8;
        f32x4 a = {0.f, 0.f, 0.f, 0.f};
        a = mfma16(aq0, *(const bf16x8*)bp, a);
        a = mfma16(aq1, *(const bf16x8*)(bp + 32), a);
#pragma unroll
        for (int i = 0; i < 4; ++i)
          qsh[h][hf * 16 + kq4 * 4 + i][tn * 16 + lr16] = a[i];
      }
    }
    // ---- qt -> registers (wave-local LDS round trip) ----
    float qt[32];
#pragma unroll
    for (int m = 0; m < 32; m += 4) {
      f32x4 v = *(const f32x4*)&qsh[h][lr32][kq1 * 32 + m];
      qt[m] = v[0]; qt[m + 1] = v[1]; qt[m + 2] = v[2]; qt[m + 3] = v[3];
    }
    // ---- phase 2: per-lane bin walk with 1-deep je prefetch ----
    float acc[32];
#pragma unroll
    for (int m = 0; m < 32; ++m) acc[m] = 0.f;
    float prs = pri[rh] * 0.125f;
    int src_next = (b0 < b1) ? je[b0] : 0;
    for (int j = b0; j < b1; ++j) {
      int src = src_next;
      if (j + 1 < b1) src_next = je[j + 1];
      const unsigned short* kp = kvb + (size_t)src * 512 + h * 128 + kq1 * 32;
      bf16x8 k0 = *(const bf16x8*)kp;
      bf16x8 k1 = *(const bf16x8*)(kp + 8);
      bf16x8 k2 = *(const bf16x8*)(kp + 16);
      bf16x8 k3 = *(const bf16x8*)(kp + 24);
      bf16x8 v0 = *(const bf16x8*)(kp + 64);
      bf16x8 v1 = *(const bf16x8*)(kp + 72);
      bf16x8 v2 = *(const bf16x8*)(kp + 80);
      bf16x8 v3 = *(const bf16x8*)(kp + 88);
      float s = 0.f;
#pragma unroll
      for (int m = 0; m < 8; ++m) {
        s += qt[m]      * bf2f((unsigned short)k0[m]);
        s += qt[8 + m]  * bf2f((unsigned short)k1[m]);
        s += qt[16 + m] * bf2f((unsigned short)k2[m]);
        s += qt[24 + m] * bf2f((unsigned short)k3[m]);
      }
      s += __shfl_xor(s, 32);
      float ex = __expf(s * prs);
      dtot += ex;
#pragma unroll
      for (int m = 0; m < 8; ++m) {
        acc[m]      += ex * bf2f((unsigned short)v0[m]);
        acc[8 + m]  += ex * bf2f((unsigned short)v1[m]);
        acc[16 + m] += ex * bf2f((unsigned short)v2[m]);
        acc[24 + m] += ex * bf2f((unsigned short)v3[m]);
      }
    }
    // ---- phase 3: stage acc -> qsh (clobbers qt), M-transform via MFMA ----
#pragma unroll
    for (int m = 0; m < 32; m += 4) {
      f32x4 v = {acc[m], acc[m + 1], acc[m + 2], acc[m + 3]};
      *(f32x4*)&qsh[h][lr32][kq1 * 32 + m] = v;
    }
#pragma unroll
    for (int hf = 0; hf < 2; ++hf) {
      bf16x8 m0, m1;
#pragma unroll
      for (int m = 0; m < 8; ++m) {
        m0[m] = (short)f2bf(qsh[h][hf * 16 + lr16][kq4 * 8 + m]);
        m1[m] = (short)f2bf(qsh[h][hf * 16 + lr16][32 + kq4 * 8 + m]);
      }
#pragma unroll
      for (int tn = 0; tn < 4; ++tn) {
        const unsigned short* bp = Mt + ((rh * 64 + tn * 16 + lr16) * 64) + kq4 * 8;
        C[hf][tn] = mfma16(m0, *(const bf16x8*)bp, C[hf][tn]);
        C[hf][tn] = mfma16(m1, *(const bf16x8*)(bp + 32), C[hf][tn]);
      }
    }
  }
  if (kq1 == 0) atomicAdd(&denom[(dt * 32 + lr32) * 4 + h], dtot);
#pragma unroll
  for (int hf = 0; hf < 2; ++hf)
#pragma unroll
    for (int tn = 0; tn < 4; ++tn)
#pragma unroll
      for (int i = 0; i < 4; ++i)
        aggh[((size_t)quarter * NN + dt * 32 + hf * 16 + kq4 * 4 + i) * 256 +
             h * 64 + tn * 16 + lr16] = f2bf(C[hf][tn][i]);
}

// ---------------- K3: final projection, 64-row x 8-col-tile blocks ------------------
__global__ __launch_bounds__(256) void k_gemm_out(
    const unsigned short* __restrict__ aggh, const float* __restrict__ denom,
    const unsigned short* __restrict__ At,
    const int* __restrict__ nperm, const int* __restrict__ toff,
    const int* __restrict__ mt64_t, const int* __restrict__ mt64_m,
    const int* __restrict__ gcnt,
    const float* __restrict__ skip, float* __restrict__ out) {
  __shared__ unsigned short bs[16][264];
  int mtile = blockIdx.x >> 1, chunk = blockIdx.x & 1;
  if (mtile >= gcnt[0]) return;
  int wave = threadIdx.x >> 6, lane = threadIdx.x & 63;
  int t = mt64_t[mtile], tm = mt64_m[mtile];
  int base = toff[t], cnt = toff[t + 1] - base;
  int lr = lane & 15, kq = lane >> 4;
  int arow = tm * 64 + wave * 16 + lr;
  int prow = base + (arow < cnt ? arow : cnt - 1);
  float dn[4];
#pragma unroll
  for (int hh = 0; hh < 4; ++hh) {
    float d = denom[prow * 4 + hh];
    dn[hh] = d > 0.f ? 1.f / d : 0.f;
  }
  const unsigned short* g = aggh + (size_t)prow * 256 + kq * 8;
  bf16x8 af[8];
#pragma unroll
  for (int s = 0; s < 8; ++s) {
    bf16x8 x0 = *(const bf16x8*)(g + s * 32);
    bf16x8 x1 = *(const bf16x8*)(g + (size_t)NN * 256 + s * 32);
    bf16x8 x2 = *(const bf16x8*)(g + (size_t)2 * NN * 256 + s * 32);
    bf16x8 x3 = *(const bf16x8*)(g + (size_t)3 * NN * 256 + s * 32);
    float dv = dn[(kq * 8 + s * 32) >> 6];
#pragma unroll
    for (int m = 0; m < 8; ++m)
      af[s][m] = (short)f2bf((bf2f((unsigned short)x0[m]) + bf2f((unsigned short)x1[m]) +
                              bf2f((unsigned short)x2[m]) + bf2f((unsigned short)x3[m])) * dv);
  }
  int nd[4]; bool wr[4];
#pragma unroll
  for (int i = 0; i < 4; ++i) {
    int crow = tm * 64 + wave * 16 + kq * 4 + i;
    wr[i] = crow < cnt;
    nd[i] = nperm[base + (wr[i] ? crow : 0)];
  }
  float sg = 1.f / (1.f + __expf(-skip[t]));
  int sc = threadIdx.x >> 4;
  int seg = threadIdx.x & 15;
  for (int tt = 0; tt < 8; ++tt) {
    int tn = chunk * 8 + tt;
    const unsigned short* wsrc = At + ((size_t)(t * 256 + tn * 16 + sc)) * 256 + seg * 16;
    __syncthreads();
    *(bf16x8*)&bs[sc][seg * 16]     = *(const bf16x8*)wsrc;
    *(bf16x8*)&bs[sc][seg * 16 + 8] = *(const bf16x8*)(wsrc + 8);
    __syncthreads();
    f32x4 acc = {0.f, 0.f, 0.f, 0.f};
#pragma unroll
    for (int s = 0; s < 8; ++s)
      acc = mfma16(af[s], *(const bf16x8*)&bs[lr][kq * 8 + s * 32], acc);
    int ccol = tn * 16 + lr;
#pragma unroll
    for (int i = 0; i < 4; ++i)
      if (wr[i]) out[nd[i] * 256 + ccol] = acc[i] * sg;
  }
}

extern "C" void kernel_launch(void* const* d_in, const int* in_sizes, int n_in,
                              void* d_out, int out_size, void* d_ws, size_t ws_size,
                              hipStream_t stream) {
  (void)in_sizes; (void)n_in; (void)out_size; (void)ws_size;
  const float* h    = (const float*)d_in[0];
  const float* Wk   = (const float*)d_in[1];
  const float* Wq   = (const float*)d_in[2];
  const float* Wv   = (const float*)d_in[3];
  const float* Wa   = (const float*)d_in[4];
  const float* ratt = (const float*)d_in[5];
  const float* rmsg = (const float*)d_in[6];
  const float* pri  = (const float*)d_in[7];
  const float* skp  = (const float*)d_in[8];
  const int* ntype  = (const int*)d_in[9];
  const int* etyp   = (const int*)d_in[10];
  const int* rowi   = (const int*)d_in[11];
  const int* coli   = (const int*)d_in[12];
  float* out = (float*)d_out;

  char* p = (char*)d_ws;
  auto alloc = [&](size_t bytes) {
    void* q = (void*)p;
    p += (bytes + 255) & ~(size_t)255;
    return q;
  };
  unsigned short* Wt   = (unsigned short*)alloc((size_t)4 * 768 * 256 * 2);
  unsigned short* At   = (unsigned short*)alloc((size_t)4 * 256 * 256 * 2);
  unsigned short* Att  = (unsigned short*)alloc((size_t)32 * 4096 * 2);
  unsigned short* Mt   = (unsigned short*)alloc((size_t)32 * 4096 * 2);
  unsigned short* kvb  = (unsigned short*)alloc((size_t)NN * 512 * 2);
  unsigned short* qb   = (unsigned short*)alloc((size_t)NN * 256 * 2);
  unsigned short* aggh = (unsigned short*)alloc((size_t)4 * NN * 256 * 2);
  float* denom = (float*)alloc((size_t)NN * 4 * 4);
  int* toff   = (int*)alloc(32);
  int* ncur   = (int*)alloc(16);
  int* c4p    = (int*)alloc((size_t)CB * 4 * 4);
  int* nperm  = (int*)alloc((size_t)NN * 4);
  int* inv    = (int*)alloc((size_t)NN * 4);
  int* bcnt   = (int*)alloc((size_t)NB * 4);
  int* boff   = (int*)alloc((size_t)(NB + 1) * 4);
  int* bcur   = (int*)alloc((size_t)NB * 4);
  int* psum   = (int*)alloc((size_t)625 * 4);
  int* je     = (int*)alloc((size_t)NE * 4);
  int* mt64_t = (int*)alloc((size_t)324 * 4);
  int* mt64_m = (int*)alloc((size_t)324 * 4);
  int* gcnt   = (int*)alloc(32);

  // node buckets (perm space)
  k_tcount<<<CB, 256, 0, stream>>>(ntype, c4p);
  k_meta<<<1, 256, 0, stream>>>(c4p, toff, ncur, mt64_t, mt64_m, gcnt);
  k_nscatter<<<CB, 256, 0, stream>>>(ntype, ncur, nperm, inv);

  // fused prep (zero + weight transposes)
  k_prep_all<<<ZB + WB + AB + RB, 256, 0, stream>>>(
      Wk, Wq, Wv, Wa, ratt, rmsg, bcnt, denom, Wt, At, Att, Mt);

  // edge CSR by (rel, perm-dst)
  k_bcount<<<(NE + 255) / 256, 256, 0, stream>>>(etyp, coli, inv, bcnt);
  k_scan1<<<625, 256, 0, stream>>>(bcnt, boff, psum);
  k_scan2<<<1, 1024, 0, stream>>>(psum);
  k_scan3<<<625, 256, 0, stream>>>(boff, bcur, psum);
  k_escatter<<<(NE + 255) / 256, 256, 0, stream>>>(etyp, rowi, coli, inv, bcur, je);

  // main pipeline
  k_gemm_kqv<<<960, 256, 0, stream>>>(h, Wt, nperm, toff, mt64_t, mt64_m, gcnt, kvb, qb);
  k_mega<<<2500, 256, 0, stream>>>(boff, je, qb, kvb, Att, Mt, pri, aggh, denom);
  k_gemm_out<<<640, 256, 0, stream>>>(aggh, denom, At, nperm, toff, mt64_t, mt64_m, gcnt,
                                      skp, out);
}

// Round 12
// 330.883 us; speedup vs baseline: 2.3595x; 1.0192x over previous
//
#include <hip/hip_runtime.h>

static constexpr int NN  = 20000;
static constexpr int NE  = 320000;
static constexpr int NTY = 4;
static constexpr int NRL = 8;
static constexpr int NB  = NRL * NN;   // 160000 bins = (rel, perm-dst)

// prep-kernel segment sizes (blocks of 256)
static constexpr int ZB   = (NB + NN * 4 + 255) / 256;  // 938  (zero bcnt+denom)
static constexpr int CB   = (NN + 255) / 256;           // 79   (type-count blocks)
static constexpr int WSEG = 192;                        // 12 mats x 16 tiles (Wk/Wq/Wv)
static constexpr int ASEG = 64;                         // 4 mats x 16 tiles (Wa)
static constexpr int RSEG = 32;                         // 32 rh, att+msg each

typedef short bf16x8 __attribute__((ext_vector_type(8)));
typedef float f32x4  __attribute__((ext_vector_type(4)));
typedef unsigned short u16x4 __attribute__((ext_vector_type(4)));

__device__ __forceinline__ unsigned short f2bf(float f) {
  unsigned u = __float_as_uint(f);
  u += 0x7fffu + ((u >> 16) & 1u);
  return (unsigned short)(u >> 16);
}
__device__ __forceinline__ float bf2f(unsigned short b) {
  return __uint_as_float(((unsigned)b) << 16);
}
__device__ __forceinline__ f32x4 mfma16(bf16x8 a, bf16x8 b, f32x4 c) {
  return __builtin_amdgcn_mfma_f32_16x16x32_bf16(a, b, c, 0, 0, 0);
}

// ---------------- fused prep: zero + tcount + coalesced tiled transposes -----------
__global__ void k_prep_all(const float* __restrict__ Wk, const float* __restrict__ Wq,
                           const float* __restrict__ Wv, const float* __restrict__ Wa,
                           const float* __restrict__ ratt, const float* __restrict__ rmsg,
                           const int* __restrict__ ntype,
                           int* bcnt, float* denom, int* c4p,
                           unsigned short* Wt, unsigned short* At,
                           unsigned short* Att, unsigned short* Mt) {
  __shared__ float tl[64][65];
  __shared__ int cc[4];
  int b = blockIdx.x, tid = threadIdx.x;
  if (b < ZB) {
    int i = b * 256 + tid;
    if (i < NB) bcnt[i] = 0;
    else if (i < NB + NN * 4) denom[i - NB] = 0.f;
    return;
  }
  b -= ZB;
  if (b < CB) {
    if (tid < 4) cc[tid] = 0;
    __syncthreads();
    int i = b * 256 + tid;
    if (i < NN) atomicAdd(&cc[ntype[i]], 1);
    __syncthreads();
    if (tid < 4) c4p[b * 4 + tid] = cc[tid];
    return;
  }
  b -= CB;
  int r4 = tid >> 6, c = tid & 63;
  if (b < WSEG) {
    int mat = b >> 4, tile = b & 15;
    int t = mat / 3, w = mat % 3;
    const float* src = (w == 0) ? Wk : (w == 1) ? Wq : Wv;
    src += (size_t)t * 65536;
    int ti = (tile >> 2) * 64, tj = (tile & 3) * 64;
#pragma unroll
    for (int p = 0; p < 16; ++p) {
      int row = p * 4 + r4;
      tl[row][c] = src[(size_t)(ti + row) * 256 + tj + c];
    }
    __syncthreads();
#pragma unroll
    for (int p = 0; p < 16; ++p) {
      int jr = p * 4 + r4;
      Wt[((size_t)(t * 768 + w * 256 + tj + jr)) * 256 + ti + c] = f2bf(tl[c][jr]);
    }
    return;
  }
  b -= WSEG;
  if (b < ASEG) {
    int t = b >> 4, tile = b & 15;
    int ti = (tile >> 2) * 64, tj = (tile & 3) * 64;
#pragma unroll
    for (int p = 0; p < 16; ++p) {
      int row = p * 4 + r4;
      tl[row][c] = Wa[(size_t)(t * 256 + ti + row) * 256 + tj + c];
    }
    __syncthreads();
#pragma unroll
    for (int p = 0; p < 16; ++p) {
      int jr = p * 4 + r4;
      At[((size_t)(t * 256 + tj + jr)) * 256 + ti + c] = f2bf(tl[c][jr]);
    }
    return;
  }
  b -= ASEG;
  {
    int rh = b;  // 0..31
    // att transpose: Att[rh][e][d] = att[rh][d][e]
#pragma unroll
    for (int p = 0; p < 16; ++p) {
      int d = p * 4 + r4;
      tl[d][c] = ratt[(size_t)rh * 4096 + d * 64 + c];
    }
    __syncthreads();
#pragma unroll
    for (int p = 0; p < 16; ++p) {
      int e = p * 4 + r4;
      Att[(size_t)rh * 4096 + e * 64 + c] = f2bf(tl[c][e]);
    }
    __syncthreads();
    // msg transpose: Mt[rh][e][d] = msg[rh][d][e]
#pragma unroll
    for (int p = 0; p < 16; ++p) {
      int d = p * 4 + r4;
      tl[d][c] = rmsg[(size_t)rh * 4096 + d * 64 + c];
    }
    __syncthreads();
#pragma unroll
    for (int p = 0; p < 16; ++p) {
      int e = p * 4 + r4;
      Mt[(size_t)rh * 4096 + e * 64 + c] = f2bf(tl[c][e]);
    }
  }
}

// meta: type offsets + 64-row tile list
__global__ void k_meta(const int* __restrict__ c4p, int* toff, int* ncur,
                       int* mt64_t, int* mt64_m, int* gcnt) {
  __shared__ int c4[4];
  __shared__ int ts[5];
  if (threadIdx.x < 4) {
    int s = 0;
    for (int b = 0; b < CB; ++b) s += c4p[b * 4 + threadIdx.x];
    c4[threadIdx.x] = s;
  }
  __syncthreads();
  if (threadIdx.x == 0) {
    int s = 0, s2 = 0;
    for (int t = 0; t < NTY; ++t) {
      toff[t] = s; ncur[t] = s; s += c4[t];
      ts[t] = s2; s2 += (c4[t] + 63) >> 6;
    }
    toff[NTY] = s; ts[NTY] = s2; gcnt[0] = s2;
  }
  __syncthreads();
  int n64 = ts[4];
  for (int i = threadIdx.x; i < n64; i += 256) {
    int t = 0;
    while (t < 3 && i >= ts[t + 1]) ++t;
    mt64_t[i] = t; mt64_m[i] = i - ts[t];
  }
}
__global__ void k_nscatter(const int* __restrict__ key, int* cur,
                           int* nperm, int* inv) {
  int i = blockIdx.x * 256 + threadIdx.x;
  if (i < NN) {
    int p = atomicAdd(&cur[key[i]], 1);
    nperm[p] = i;
    inv[i] = p;
  }
}

// ---------------- edge CSR by (rel, perm-dst) ----------------
__global__ void k_bcount(const int* __restrict__ etyp, const int* __restrict__ coli,
                         const int* __restrict__ inv, int* bcnt) {
  int e = blockIdx.x * 256 + threadIdx.x;
  if (e < NE) atomicAdd(&bcnt[etyp[e] * NN + inv[coli[e]]], 1);
}
__global__ void k_scan1(const int* cnt, int* off, int* psum) {
  __shared__ int sm[256];
  int i = blockIdx.x * 256 + threadIdx.x;
  int v = cnt[i];
  sm[threadIdx.x] = v;
  __syncthreads();
  for (int d = 1; d < 256; d <<= 1) {
    int t = (threadIdx.x >= d) ? sm[threadIdx.x - d] : 0;
    __syncthreads();
    sm[threadIdx.x] += t;
    __syncthreads();
  }
  off[i] = sm[threadIdx.x] - v;
  if (threadIdx.x == 255) psum[blockIdx.x] = sm[255];
}
__global__ void k_scan2(int* psum) {
  __shared__ int sm[1024];
  int t = threadIdx.x;
  int v = (t < 625) ? psum[t] : 0;
  sm[t] = v;
  __syncthreads();
  for (int d = 1; d < 1024; d <<= 1) {
    int x = (t >= d) ? sm[t - d] : 0;
    __syncthreads();
    sm[t] += x;
    __syncthreads();
  }
  if (t < 625) psum[t] = sm[t] - v;
}
__global__ void k_scan3(int* off, int* cur, const int* psum) {
  int i = blockIdx.x * 256 + threadIdx.x;
  int v = off[i] + psum[blockIdx.x];
  off[i] = v; cur[i] = v;
  if (i == 0) off[NB] = NE;
}
__global__ void k_escatter(const int* __restrict__ etyp, const int* __restrict__ rowi,
                           const int* __restrict__ coli, const int* __restrict__ inv,
                           int* cur, int* je) {
  int e = blockIdx.x * 256 + threadIdx.x;
  if (e >= NE) return;
  int bin = etyp[e] * NN + inv[coli[e]];
  int j = atomicAdd(&cur[bin], 1);
  je[j] = inv[rowi[e]];
}

// ---------------- K1: typed K/Q/V projection, 64-row x 16-col-tile blocks ------------
__global__ __launch_bounds__(256) void k_gemm_kqv(
    const float* __restrict__ hsrc, const unsigned short* __restrict__ Wt,
    const int* __restrict__ nperm, const int* __restrict__ toff,
    const int* __restrict__ mt64_t, const int* __restrict__ mt64_m,
    const int* __restrict__ gcnt,
    unsigned short* __restrict__ kvb, unsigned short* __restrict__ qb) {
  __shared__ unsigned short bs[16][264];
  int mtile = blockIdx.x / 3, chunk = blockIdx.x % 3;
  if (mtile >= gcnt[0]) return;
  int wave = threadIdx.x >> 6, lane = threadIdx.x & 63;
  int t = mt64_t[mtile], tm = mt64_m[mtile];
  int base = toff[t], cnt = toff[t + 1] - base;
  int lr = lane & 15, kq = lane >> 4;
  int arow = tm * 64 + wave * 16 + lr;
  int prow = base + (arow < cnt ? arow : cnt - 1);
  int node = nperm[prow];
  const float* ap = hsrc + (size_t)node * 256 + kq * 8;
  bf16x8 af[8];
#pragma unroll
  for (int s = 0; s < 8; ++s) {
    f32x4 x0 = *(const f32x4*)(ap + s * 32);
    f32x4 x1 = *(const f32x4*)(ap + s * 32 + 4);
    bf16x8 o;
    o[0] = (short)f2bf(x0[0]); o[1] = (short)f2bf(x0[1]);
    o[2] = (short)f2bf(x0[2]); o[3] = (short)f2bf(x0[3]);
    o[4] = (short)f2bf(x1[0]); o[5] = (short)f2bf(x1[1]);
    o[6] = (short)f2bf(x1[2]); o[7] = (short)f2bf(x1[3]);
    af[s] = o;
  }
  int pr[4]; bool wr[4];
#pragma unroll
  for (int i = 0; i < 4; ++i) {
    int crow = tm * 64 + wave * 16 + kq * 4 + i;
    wr[i] = crow < cnt;
    pr[i] = base + (wr[i] ? crow : 0);
  }
  int sc = threadIdx.x >> 4;     // staging col 0..15
  int seg = threadIdx.x & 15;    // staging 16-short segment
  for (int tt = 0; tt < 16; ++tt) {
    int tn = chunk * 16 + tt;
    const unsigned short* wsrc = Wt + ((size_t)(t * 768 + tn * 16 + sc)) * 256 + seg * 16;
    __syncthreads();
    *(bf16x8*)&bs[sc][seg * 16]     = *(const bf16x8*)wsrc;
    *(bf16x8*)&bs[sc][seg * 16 + 8] = *(const bf16x8*)(wsrc + 8);
    __syncthreads();
    f32x4 acc = {0.f, 0.f, 0.f, 0.f};
#pragma unroll
    for (int s = 0; s < 8; ++s)
      acc = mfma16(af[s], *(const bf16x8*)&bs[lr][kq * 8 + s * 32], acc);
    int ccol = tn * 16 + lr;
#pragma unroll
    for (int i = 0; i < 4; ++i) {
      if (wr[i]) {
        unsigned short v = f2bf(acc[i]);
        if (ccol < 256)
          kvb[(size_t)pr[i] * 512 + (ccol >> 6) * 128 + (ccol & 63)] = v;
        else if (ccol < 512)
          qb[(size_t)pr[i] * 256 + (ccol - 256)] = v;
        else {
          int c = ccol - 512;
          kvb[(size_t)pr[i] * 512 + (c >> 6) * 128 + 64 + (c & 63)] = v;
        }
      }
    }
  }
}

// ---------------- K2: mega — 32 bins/wave, f32 LDS + je prefetch --------------------
// block = (dst-tile of 32, relation-quarter = 2 rels); wave = head.
__global__ __launch_bounds__(256) void k_mega(
    const int* __restrict__ boff, const int* __restrict__ je,
    const unsigned short* __restrict__ qb, const unsigned short* __restrict__ kvb,
    const unsigned short* __restrict__ Att, const unsigned short* __restrict__ Mt,
    const float* __restrict__ pri, unsigned short* __restrict__ aggh,
    float* __restrict__ denom) {
  __shared__ float qsh[4][32][68];   // [head][dst_local][dim] f32, stride 68
  int dt = blockIdx.x >> 2, quarter = blockIdx.x & 3;
  int h = threadIdx.x >> 6, lane = threadIdx.x & 63;
  int lr16 = lane & 15, kq4 = lane >> 4;    // MFMA mapping
  int lr32 = lane & 31, kq1 = lane >> 5;    // edge-loop mapping
  int r0 = quarter * 2;
  float dtot = 0.f;
  f32x4 C[2][4] = {{{0.f,0.f,0.f,0.f},{0.f,0.f,0.f,0.f},{0.f,0.f,0.f,0.f},{0.f,0.f,0.f,0.f}},
                   {{0.f,0.f,0.f,0.f},{0.f,0.f,0.f,0.f},{0.f,0.f,0.f,0.f},{0.f,0.f,0.f,0.f}}};
  for (int rr = 0; rr < 2; ++rr) {
    int r = r0 + rr;
    int rh = r * 4 + h;
    int bin = r * NN + dt * 32 + lr32;
    int b0 = boff[bin], b1 = boff[bin + 1];
    // ---- phase 1: qt = q @ A_r^T via MFMA (two 16-row halves) -> qsh f32 ----
#pragma unroll
    for (int hf = 0; hf < 2; ++hf) {
      const unsigned short* ap = qb + (size_t)(dt * 32 + hf * 16 + lr16) * 256 + h * 64 + kq4 * 8;
      bf16x8 aq0 = *(const bf16x8*)ap;
      bf16x8 aq1 = *(const bf16x8*)(ap + 32);
#pragma unroll
      for (int tn = 0; tn < 4; ++tn) {
        const unsigned short* bp = Att + ((rh * 64 + tn * 16 + lr16) * 64) + kq4 * 8;
        f32x4 a = {0.f, 0.f, 0.f, 0.f};
        a = mfma16(aq0, *(const bf16x8*)bp, a);
        a = mfma16(aq1, *(const bf16x8*)(bp + 32), a);
#pragma unroll
        for (int i = 0; i < 4; ++i)
          qsh[h][hf * 16 + kq4 * 4 + i][tn * 16 + lr16] = a[i];
      }
    }
    // ---- qt -> registers (wave-local LDS round trip) ----
    float qt[32];
#pragma unroll
    for (int m = 0; m < 32; m += 4) {
      f32x4 v = *(const f32x4*)&qsh[h][lr32][kq1 * 32 + m];
      qt[m] = v[0]; qt[m + 1] = v[1]; qt[m + 2] = v[2]; qt[m + 3] = v[3];
    }
    // ---- phase 2: per-lane bin walk with 1-deep je prefetch ----
    float acc[32];
#pragma unroll
    for (int m = 0; m < 32; ++m) acc[m] = 0.f;
    float prs = pri[rh] * 0.125f;
    int src_next = (b0 < b1) ? je[b0] : 0;
    for (int j = b0; j < b1; ++j) {
      int src = src_next;
      if (j + 1 < b1) src_next = je[j + 1];
      const unsigned short* kp = kvb + (size_t)src * 512 + h * 128 + kq1 * 32;
      bf16x8 k0 = *(const bf16x8*)kp;
      bf16x8 k1 = *(const bf16x8*)(kp + 8);
      bf16x8 k2 = *(const bf16x8*)(kp + 16);
      bf16x8 k3 = *(const bf16x8*)(kp + 24);
      bf16x8 v0 = *(const bf16x8*)(kp + 64);
      bf16x8 v1 = *(const bf16x8*)(kp + 72);
      bf16x8 v2 = *(const bf16x8*)(kp + 80);
      bf16x8 v3 = *(const bf16x8*)(kp + 88);
      float s = 0.f;
#pragma unroll
      for (int m = 0; m < 8; ++m) {
        s += qt[m]      * bf2f((unsigned short)k0[m]);
        s += qt[8 + m]  * bf2f((unsigned short)k1[m]);
        s += qt[16 + m] * bf2f((unsigned short)k2[m]);
        s += qt[24 + m] * bf2f((unsigned short)k3[m]);
      }
      s += __shfl_xor(s, 32);
      float ex = __expf(s * prs);
      dtot += ex;
#pragma unroll
      for (int m = 0; m < 8; ++m) {
        acc[m]      += ex * bf2f((unsigned short)v0[m]);
        acc[8 + m]  += ex * bf2f((unsigned short)v1[m]);
        acc[16 + m] += ex * bf2f((unsigned short)v2[m]);
        acc[24 + m] += ex * bf2f((unsigned short)v3[m]);
      }
    }
    // ---- phase 3: stage acc -> qsh (clobbers qt), M-transform via MFMA ----
#pragma unroll
    for (int m = 0; m < 32; m += 4) {
      f32x4 v = {acc[m], acc[m + 1], acc[m + 2], acc[m + 3]};
      *(f32x4*)&qsh[h][lr32][kq1 * 32 + m] = v;
    }
#pragma unroll
    for (int hf = 0; hf < 2; ++hf) {
      bf16x8 m0, m1;
#pragma unroll
      for (int m = 0; m < 8; ++m) {
        m0[m] = (short)f2bf(qsh[h][hf * 16 + lr16][kq4 * 8 + m]);
        m1[m] = (short)f2bf(qsh[h][hf * 16 + lr16][32 + kq4 * 8 + m]);
      }
#pragma unroll
      for (int tn = 0; tn < 4; ++tn) {
        const unsigned short* bp = Mt + ((rh * 64 + tn * 16 + lr16) * 64) + kq4 * 8;
        C[hf][tn] = mfma16(m0, *(const bf16x8*)bp, C[hf][tn]);
        C[hf][tn] = mfma16(m1, *(const bf16x8*)(bp + 32), C[hf][tn]);
      }
    }
  }
  if (kq1 == 0) atomicAdd(&denom[(dt * 32 + lr32) * 4 + h], dtot);
#pragma unroll
  for (int hf = 0; hf < 2; ++hf)
#pragma unroll
    for (int tn = 0; tn < 4; ++tn)
#pragma unroll
      for (int i = 0; i < 4; ++i)
        aggh[((size_t)quarter * NN + dt * 32 + hf * 16 + kq4 * 4 + i) * 256 +
             h * 64 + tn * 16 + lr16] = f2bf(C[hf][tn][i]);
}

// ---------------- K3: final projection, 64-row x 8-col-tile blocks ------------------
__global__ __launch_bounds__(256) void k_gemm_out(
    const unsigned short* __restrict__ aggh, const float* __restrict__ denom,
    const unsigned short* __restrict__ At,
    const int* __restrict__ nperm, const int* __restrict__ toff,
    const int* __restrict__ mt64_t, const int* __restrict__ mt64_m,
    const int* __restrict__ gcnt,
    const float* __restrict__ skip, float* __restrict__ out) {
  __shared__ unsigned short bs[16][264];
  int mtile = blockIdx.x >> 1, chunk = blockIdx.x & 1;
  if (mtile >= gcnt[0]) return;
  int wave = threadIdx.x >> 6, lane = threadIdx.x & 63;
  int t = mt64_t[mtile], tm = mt64_m[mtile];
  int base = toff[t], cnt = toff[t + 1] - base;
  int lr = lane & 15, kq = lane >> 4;
  int arow = tm * 64 + wave * 16 + lr;
  int prow = base + (arow < cnt ? arow : cnt - 1);
  float dn[4];
#pragma unroll
  for (int hh = 0; hh < 4; ++hh) {
    float d = denom[prow * 4 + hh];
    dn[hh] = d > 0.f ? 1.f / d : 0.f;
  }
  const unsigned short* g = aggh + (size_t)prow * 256 + kq * 8;
  bf16x8 af[8];
#pragma unroll
  for (int s = 0; s < 8; ++s) {
    bf16x8 x0 = *(const bf16x8*)(g + s * 32);
    bf16x8 x1 = *(const bf16x8*)(g + (size_t)NN * 256 + s * 32);
    bf16x8 x2 = *(const bf16x8*)(g + (size_t)2 * NN * 256 + s * 32);
    bf16x8 x3 = *(const bf16x8*)(g + (size_t)3 * NN * 256 + s * 32);
    float dv = dn[(kq * 8 + s * 32) >> 6];
#pragma unroll
    for (int m = 0; m < 8; ++m)
      af[s][m] = (short)f2bf((bf2f((unsigned short)x0[m]) + bf2f((unsigned short)x1[m]) +
                              bf2f((unsigned short)x2[m]) + bf2f((unsigned short)x3[m])) * dv);
  }
  int nd[4]; bool wr[4];
#pragma unroll
  for (int i = 0; i < 4; ++i) {
    int crow = tm * 64 + wave * 16 + kq * 4 + i;
    wr[i] = crow < cnt;
    nd[i] = nperm[base + (wr[i] ? crow : 0)];
  }
  float sg = 1.f / (1.f + __expf(-skip[t]));
  int sc = threadIdx.x >> 4;
  int seg = threadIdx.x & 15;
  for (int tt = 0; tt < 8; ++tt) {
    int tn = chunk * 8 + tt;
    const unsigned short* wsrc = At + ((size_t)(t * 256 + tn * 16 + sc)) * 256 + seg * 16;
    __syncthreads();
    *(bf16x8*)&bs[sc][seg * 16]     = *(const bf16x8*)wsrc;
    *(bf16x8*)&bs[sc][seg * 16 + 8] = *(const bf16x8*)(wsrc + 8);
    __syncthreads();
    f32x4 acc = {0.f, 0.f, 0.f, 0.f};
#pragma unroll
    for (int s = 0; s < 8; ++s)
      acc = mfma16(af[s], *(const bf16x8*)&bs[lr][kq * 8 + s * 32], acc);
    int ccol = tn * 16 + lr;
#pragma unroll
    for (int i = 0; i < 4; ++i)
      if (wr[i]) out[nd[i] * 256 + ccol] = acc[i] * sg;
  }
}

extern "C" void kernel_launch(void* const* d_in, const int* in_sizes, int n_in,
                              void* d_out, int out_size, void* d_ws, size_t ws_size,
                              hipStream_t stream) {
  (void)in_sizes; (void)n_in; (void)out_size; (void)ws_size;
  const float* h    = (const float*)d_in[0];
  const float* Wk   = (const float*)d_in[1];
  const float* Wq   = (const float*)d_in[2];
  const float* Wv   = (const float*)d_in[3];
  const float* Wa   = (const float*)d_in[4];
  const float* ratt = (const float*)d_in[5];
  const float* rmsg = (const float*)d_in[6];
  const float* pri  = (const float*)d_in[7];
  const float* skp  = (const float*)d_in[8];
  const int* ntype  = (const int*)d_in[9];
  const int* etyp   = (const int*)d_in[10];
  const int* rowi   = (const int*)d_in[11];
  const int* coli   = (const int*)d_in[12];
  float* out = (float*)d_out;

  char* p = (char*)d_ws;
  auto alloc = [&](size_t bytes) {
    void* q = (void*)p;
    p += (bytes + 255) & ~(size_t)255;
    return q;
  };
  unsigned short* Wt   = (unsigned short*)alloc((size_t)4 * 768 * 256 * 2);
  unsigned short* At   = (unsigned short*)alloc((size_t)4 * 256 * 256 * 2);
  unsigned short* Att  = (unsigned short*)alloc((size_t)32 * 4096 * 2);
  unsigned short* Mt   = (unsigned short*)alloc((size_t)32 * 4096 * 2);
  unsigned short* kvb  = (unsigned short*)alloc((size_t)NN * 512 * 2);
  unsigned short* qb   = (unsigned short*)alloc((size_t)NN * 256 * 2);
  unsigned short* aggh = (unsigned short*)alloc((size_t)4 * NN * 256 * 2);
  float* denom = (float*)alloc((size_t)NN * 4 * 4);
  int* toff   = (int*)alloc(32);
  int* ncur   = (int*)alloc(16);
  int* c4p    = (int*)alloc((size_t)CB * 4 * 4);
  int* nperm  = (int*)alloc((size_t)NN * 4);
  int* inv    = (int*)alloc((size_t)NN * 4);
  int* bcnt   = (int*)alloc((size_t)NB * 4);
  int* boff   = (int*)alloc((size_t)(NB + 1) * 4);
  int* bcur   = (int*)alloc((size_t)NB * 4);
  int* psum   = (int*)alloc((size_t)625 * 4);
  int* je     = (int*)alloc((size_t)NE * 4);
  int* mt64_t = (int*)alloc((size_t)324 * 4);
  int* mt64_m = (int*)alloc((size_t)324 * 4);
  int* gcnt   = (int*)alloc(32);

  // fused prep (zero + type-count + coalesced transposes)
  k_prep_all<<<ZB + CB + WSEG + ASEG + RSEG, 256, 0, stream>>>(
      Wk, Wq, Wv, Wa, ratt, rmsg, ntype, bcnt, denom, c4p, Wt, At, Att, Mt);
  k_meta<<<1, 256, 0, stream>>>(c4p, toff, ncur, mt64_t, mt64_m, gcnt);
  k_nscatter<<<CB, 256, 0, stream>>>(ntype, ncur, nperm, inv);

  // edge CSR by (rel, perm-dst)
  k_bcount<<<(NE + 255) / 256, 256, 0, stream>>>(etyp, coli, inv, bcnt);
  k_scan1<<<625, 256, 0, stream>>>(bcnt, boff, psum);
  k_scan2<<<1, 1024, 0, stream>>>(psum);
  k_scan3<<<625, 256, 0, stream>>>(boff, bcur, psum);
  k_escatter<<<(NE + 255) / 256, 256, 0, stream>>>(etyp, rowi, coli, inv, bcur, je);

  // main pipeline
  k_gemm_kqv<<<960, 256, 0, stream>>>(h, Wt, nperm, toff, mt64_t, mt64_m, gcnt, kvb, qb);
  k_mega<<<2500, 256, 0, stream>>>(boff, je, qb, kvb, Att, Mt, pri, aggh, denom);
  k_gemm_out<<<640, 256, 0, stream>>>(aggh, denom, At, nperm, toff, mt64_t, mt64_m, gcnt,
                                      skp, out);
}